// Round 1
// baseline (597.197 us; speedup 1.0000x reference)
//
#include <hip/hip_runtime.h>

#define N_NODES 50000
#define N_EDGES 300000
#define DFEAT 256
#define EPS_F 1e-12f

// ---------------------------------------------------------------------------
// Graph preprocessing kernels
// ---------------------------------------------------------------------------

__global__ void deg_kernel(const int* __restrict__ ei, const float* __restrict__ ew,
                           float* __restrict__ deg_out, float* __restrict__ deg_in,
                           int* __restrict__ cnt) {
    int e = blockIdx.x * blockDim.x + threadIdx.x;
    if (e >= N_EDGES) return;
    int s = ei[e];
    int d = ei[N_EDGES + e];
    float w = ew[e];
    atomicAdd(&deg_out[s], w);
    atomicAdd(&deg_in[d], w);
    atomicAdd(&cnt[d], 1);
}

__global__ void norm_kernel(const int* __restrict__ ei, const float* __restrict__ ew,
                            const float* __restrict__ deg_out, const float* __restrict__ deg_in,
                            float* __restrict__ nrm) {
    int e = blockIdx.x * blockDim.x + threadIdx.x;
    if (e >= N_EDGES) return;
    int s = ei[e];
    int d = ei[N_EDGES + e];
    nrm[e] = ew[e] * rsqrtf(deg_out[s] * deg_in[d] + EPS_F);
}

// Single-block exclusive scan over cnt[0..N_NODES) -> row_ptr[0..N_NODES]
__global__ void scan_kernel(const int* __restrict__ cnt, int* __restrict__ row_ptr) {
    __shared__ int sh[1024];
    __shared__ int carry;
    if (threadIdx.x == 0) carry = 0;
    __syncthreads();
    for (int base = 0; base < N_NODES; base += 1024) {
        int i = base + (int)threadIdx.x;
        int v = (i < N_NODES) ? cnt[i] : 0;
        sh[threadIdx.x] = v;
        __syncthreads();
        for (int off = 1; off < 1024; off <<= 1) {
            int t = (threadIdx.x >= (unsigned)off) ? sh[threadIdx.x - off] : 0;
            __syncthreads();
            sh[threadIdx.x] += t;
            __syncthreads();
        }
        int excl = sh[threadIdx.x] - v;
        if (i < N_NODES) row_ptr[i] = carry + excl;  // reads carry BEFORE update
        __syncthreads();
        if (threadIdx.x == 1023) carry += sh[1023];
        __syncthreads();
    }
    if (threadIdx.x == 0) row_ptr[N_NODES] = carry;
}

// Scatter edges into CSR slots; store src id and norm weight directly.
__global__ void fill_kernel(const int* __restrict__ ei, const float* __restrict__ nrm,
                            const int* __restrict__ row_ptr, int* __restrict__ cur,
                            int* __restrict__ csr_src, float* __restrict__ csr_w) {
    int e = blockIdx.x * blockDim.x + threadIdx.x;
    if (e >= N_EDGES) return;
    int d = ei[N_EDGES + e];
    int pos = atomicAdd(&cur[d], 1);
    int slot = row_ptr[d] + pos;
    csr_src[slot] = ei[e];
    csr_w[slot] = nrm[e];
}

// ---------------------------------------------------------------------------
// fp32 tiled GEMM: C[M,256] = A[M,256] @ B[256,256] (+ bias if BIAS)
// 64x64 tile, 256 threads (16x16), 4x4 micro-tile, BK=16
// ---------------------------------------------------------------------------

template <bool BIAS>
__global__ __launch_bounds__(256) void gemm_kernel(const float* __restrict__ A,
                                                   const float* __restrict__ B,
                                                   const float* __restrict__ bias,
                                                   float* __restrict__ C, int M) {
    __shared__ float as[16][68];  // K-major A tile; pad 68 for bank spread + 16B align
    __shared__ float bs[16][68];

    const int t = threadIdx.x;
    const int tx = t & 15;
    const int ty = t >> 4;
    const int m0 = blockIdx.x * 64;
    const int n0 = blockIdx.y * 64;

    // staging assignment (each thread loads 4 contiguous floats)
    const int a_row = t >> 2;          // 0..63
    const int a_col = (t & 3) << 2;    // 0,4,8,12
    const int b_row = t >> 4;          // 0..15
    const int b_col = (t & 15) << 2;   // 0..60

    float acc[4][4] = {};

    for (int k0 = 0; k0 < 256; k0 += 16) {
        float4 av;
        int gr = m0 + a_row;
        if (gr < M)
            av = *(const float4*)&A[(size_t)gr * DFEAT + k0 + a_col];
        else
            av = make_float4(0.f, 0.f, 0.f, 0.f);
        as[a_col + 0][a_row] = av.x;
        as[a_col + 1][a_row] = av.y;
        as[a_col + 2][a_row] = av.z;
        as[a_col + 3][a_row] = av.w;

        float4 bv = *(const float4*)&B[(size_t)(k0 + b_row) * DFEAT + n0 + b_col];
        *(float4*)&bs[b_row][b_col] = bv;

        __syncthreads();

#pragma unroll
        for (int k = 0; k < 16; ++k) {
            float4 a4 = *(const float4*)&as[k][ty << 2];
            float4 b4 = *(const float4*)&bs[k][tx << 2];
            acc[0][0] += a4.x * b4.x; acc[0][1] += a4.x * b4.y;
            acc[0][2] += a4.x * b4.z; acc[0][3] += a4.x * b4.w;
            acc[1][0] += a4.y * b4.x; acc[1][1] += a4.y * b4.y;
            acc[1][2] += a4.y * b4.z; acc[1][3] += a4.y * b4.w;
            acc[2][0] += a4.z * b4.x; acc[2][1] += a4.z * b4.y;
            acc[2][2] += a4.z * b4.z; acc[2][3] += a4.z * b4.w;
            acc[3][0] += a4.w * b4.x; acc[3][1] += a4.w * b4.y;
            acc[3][2] += a4.w * b4.z; acc[3][3] += a4.w * b4.w;
        }
        __syncthreads();
    }

#pragma unroll
    for (int i = 0; i < 4; ++i) {
        int row = m0 + (ty << 2) + i;
        if (row >= M) continue;
        int col = n0 + (tx << 2);
        float4 v;
        v.x = acc[i][0]; v.y = acc[i][1]; v.z = acc[i][2]; v.w = acc[i][3];
        if (BIAS) {
            v.x += bias[col + 0]; v.y += bias[col + 1];
            v.z += bias[col + 2]; v.w += bias[col + 3];
        }
        *(float4*)&C[(size_t)row * DFEAT + col] = v;
    }
}

// ---------------------------------------------------------------------------
// Aggregation: out[v,:] = relu(sum_e w_e * xt[src_e,:] + bias)
// one block (256 threads) per node, one lane per feature
// ---------------------------------------------------------------------------

__global__ __launch_bounds__(256) void agg_relu_kernel(const float* __restrict__ xt,
                                                       const int* __restrict__ row_ptr,
                                                       const int* __restrict__ csr_src,
                                                       const float* __restrict__ csr_w,
                                                       const float* __restrict__ bias,
                                                       float* __restrict__ out) {
    int v = blockIdx.x;
    int d = threadIdx.x;
    int s0 = row_ptr[v];
    int s1 = row_ptr[v + 1];
    float acc = 0.f;
    for (int i = s0; i < s1; ++i) {
        int s = csr_src[i];
        float w = csr_w[i];
        acc += xt[(size_t)s * DFEAT + d] * w;
    }
    float r = acc + bias[d];
    out[(size_t)v * DFEAT + d] = r > 0.f ? r : 0.f;
}

// ---------------------------------------------------------------------------

extern "C" void kernel_launch(void* const* d_in, const int* in_sizes, int n_in,
                              void* d_out, int out_size, void* d_ws, size_t ws_size,
                              hipStream_t stream) {
    (void)in_sizes; (void)n_in; (void)out_size; (void)ws_size;
    const float* h5 = (const float*)d_in[0];
    const int*   ei = (const int*)d_in[1];   // [2, E] int32
    const float* ew = (const float*)d_in[2];
    const float* W6 = (const float*)d_in[3];
    const float* b6 = (const float*)d_in[4];
    const float* W7 = (const float*)d_in[5];
    const float* b7 = (const float*)d_in[6];
    const float* Wp = (const float*)d_in[7];
    const float* bp = (const float*)d_in[8];
    float* out = (float*)d_out;

    char* ws = (char*)d_ws;
    size_t off = 0;
    auto alloc = [&](size_t bytes) -> void* {
        void* p = ws + off;
        off = (off + bytes + 255) & ~(size_t)255;
        return p;
    };

    float* deg_out = (float*)alloc(N_NODES * 4);
    float* deg_in  = (float*)alloc(N_NODES * 4);
    int*   cnt     = (int*)alloc(N_NODES * 4);
    int*   row_ptr = (int*)alloc((N_NODES + 1) * 4);
    float* nrm     = (float*)alloc(N_EDGES * 4);
    int*   csr_src = (int*)alloc(N_EDGES * 4);
    float* csr_w   = (float*)alloc(N_EDGES * 4);
    float* buf1    = (float*)alloc((size_t)N_NODES * DFEAT * 4);
    float* buf2    = (float*)alloc((size_t)N_NODES * DFEAT * 4);

    const int EB = (N_EDGES + 255) / 256;
    dim3 ggrid((N_NODES + 63) / 64, 4);

    hipMemsetAsync(deg_out, 0, N_NODES * 4, stream);
    hipMemsetAsync(deg_in, 0, N_NODES * 4, stream);
    hipMemsetAsync(cnt, 0, N_NODES * 4, stream);

    deg_kernel<<<EB, 256, 0, stream>>>(ei, ew, deg_out, deg_in, cnt);
    norm_kernel<<<EB, 256, 0, stream>>>(ei, ew, deg_out, deg_in, nrm);
    scan_kernel<<<1, 1024, 0, stream>>>(cnt, row_ptr);
    hipMemsetAsync(cnt, 0, N_NODES * 4, stream);
    fill_kernel<<<EB, 256, 0, stream>>>(ei, nrm, row_ptr, cnt, csr_src, csr_w);

    // layer 1: xt = h5 @ W6 ; h6 = relu(agg + b6)
    gemm_kernel<false><<<ggrid, 256, 0, stream>>>(h5, W6, nullptr, buf1, N_NODES);
    agg_relu_kernel<<<N_NODES, 256, 0, stream>>>(buf1, row_ptr, csr_src, csr_w, b6, buf2);

    // layer 2: xt = h6 @ W7 ; h7 = relu(agg + b7)
    gemm_kernel<false><<<ggrid, 256, 0, stream>>>(buf2, W7, nullptr, buf1, N_NODES);
    agg_relu_kernel<<<N_NODES, 256, 0, stream>>>(buf1, row_ptr, csr_src, csr_w, b7, buf2);

    // head: out = h7 @ Wp + bp
    gemm_kernel<true><<<ggrid, 256, 0, stream>>>(buf2, Wp, bp, out, N_NODES);
}

// Round 2
// 447.210 us; speedup vs baseline: 1.3354x; 1.3354x over previous
//
#include <hip/hip_runtime.h>

#define N_NODES 50000
#define N_EDGES 300000
#define DFEAT 256
#define EPS_F 1e-12f

typedef short bf16x8 __attribute__((ext_vector_type(8)));
typedef float f32x4 __attribute__((ext_vector_type(4)));

__device__ inline unsigned short f2bf(float f) {
    unsigned int u = __float_as_uint(f);
    u += 0x7FFFu + ((u >> 16) & 1u);   // round to nearest even
    return (unsigned short)(u >> 16);
}
__device__ inline float bf2f(unsigned short h) {
    return __uint_as_float(((unsigned int)h) << 16);
}

static __device__ inline f32x4 mfma_bf16(bf16x8 a, bf16x8 b, f32x4 c) {
    return __builtin_amdgcn_mfma_f32_16x16x32_bf16(a, b, c, 0, 0, 0);
}

// ---------------------------------------------------------------------------
// Graph preprocessing
// ---------------------------------------------------------------------------

__global__ void deg_kernel(const int* __restrict__ ei, const float* __restrict__ ew,
                           float* __restrict__ deg_out, float* __restrict__ deg_in,
                           int* __restrict__ cnt) {
    int e = blockIdx.x * blockDim.x + threadIdx.x;
    if (e >= N_EDGES) return;
    int s = ei[e];
    int d = ei[N_EDGES + e];
    float w = ew[e];
    atomicAdd(&deg_out[s], w);
    atomicAdd(&deg_in[d], w);
    atomicAdd(&cnt[d], 1);
}

__global__ void norm_kernel(const int* __restrict__ ei, const float* __restrict__ ew,
                            const float* __restrict__ deg_out, const float* __restrict__ deg_in,
                            float* __restrict__ nrm) {
    int e = blockIdx.x * blockDim.x + threadIdx.x;
    if (e >= N_EDGES) return;
    int s = ei[e];
    int d = ei[N_EDGES + e];
    nrm[e] = ew[e] * rsqrtf(deg_out[s] * deg_in[d] + EPS_F);
}

// Chunked single-block exclusive scan: 49 serial elems/thread + one block scan.
__global__ void scan_kernel(const int* __restrict__ cnt, int* __restrict__ row_ptr) {
    __shared__ int sh[1024];
    const int CH = (N_NODES + 1023) / 1024;  // 49
    int t = threadIdx.x;
    int b = t * CH;
    int e = b + CH < N_NODES ? b + CH : N_NODES;
    int s = 0;
    for (int i = b; i < e; ++i) s += cnt[i];
    sh[t] = s;
    __syncthreads();
    for (int off = 1; off < 1024; off <<= 1) {
        int val = (t >= off) ? sh[t - off] : 0;
        __syncthreads();
        sh[t] += val;
        __syncthreads();
    }
    int run = sh[t] - s;  // exclusive prefix of this chunk
    for (int i = b; i < e; ++i) { row_ptr[i] = run; run += cnt[i]; }
    if (t == 1023) row_ptr[N_NODES] = sh[1023];
}

__global__ void fill_kernel(const int* __restrict__ ei, const float* __restrict__ nrm,
                            const int* __restrict__ row_ptr, int* __restrict__ cur,
                            int* __restrict__ csr_src, float* __restrict__ csr_w) {
    int e = blockIdx.x * blockDim.x + threadIdx.x;
    if (e >= N_EDGES) return;
    int d = ei[N_EDGES + e];
    int pos = atomicAdd(&cur[d], 1);
    int slot = row_ptr[d] + pos;
    csr_src[slot] = ei[e];
    csr_w[slot] = nrm[e];
}

// ---------------------------------------------------------------------------
// hi/lo bf16 split of inputs
// ---------------------------------------------------------------------------

// X fp32 [N_NODES,256] -> Ahi, Alo bf16; 4 elems/thread
__global__ __launch_bounds__(256) void asplit_kernel(const float* __restrict__ X,
                                                     unsigned short* __restrict__ Ahi,
                                                     unsigned short* __restrict__ Alo) {
    size_t id = (size_t)(blockIdx.x * 256 + threadIdx.x) * 4;
    float4 v = *(const float4*)&X[id];
    ushort4 h, l;
    h.x = f2bf(v.x); l.x = f2bf(v.x - bf2f(h.x));
    h.y = f2bf(v.y); l.y = f2bf(v.y - bf2f(h.y));
    h.z = f2bf(v.z); l.z = f2bf(v.z - bf2f(h.z));
    h.w = f2bf(v.w); l.w = f2bf(v.w - bf2f(h.w));
    *(ushort4*)&Ahi[id] = h;
    *(ushort4*)&Alo[id] = l;
}

// W [256,256] fp32 -> transposed hi/lo bf16 BT[n][k]; grid.y selects weight
__global__ __launch_bounds__(256) void wsplit_kernel(const float* __restrict__ W6,
                                                     const float* __restrict__ W7,
                                                     const float* __restrict__ Wp,
                                                     unsigned short* __restrict__ wt_hi,
                                                     unsigned short* __restrict__ wt_lo) {
    int id = blockIdx.x * 256 + threadIdx.x;  // 0..65535
    int wsel = blockIdx.y;
    const float* W = (wsel == 0) ? W6 : (wsel == 1) ? W7 : Wp;
    int n = id & 255, k = id >> 8;
    float v = W[k * 256 + n];
    unsigned short h = f2bf(v);
    wt_hi[(size_t)wsel * 65536 + n * 256 + k] = h;
    wt_lo[(size_t)wsel * 65536 + n * 256 + k] = f2bf(v - bf2f(h));
}

// ---------------------------------------------------------------------------
// MFMA GEMM: C[M,256] = (Ahi+Alo)[M,256] @ (Bhi+Blo)[256,256]
// B given pre-transposed as BT[n][k]. 128x128 tile, 4 waves (2x2), each wave
// 64x64 via 4x4 frags of 16x16x32. bf16x3: hi*hi + lo*hi + hi*lo.
// MODE 0: bf16 output (gather buffer). MODE 1: f32 output + bias (head).
// ---------------------------------------------------------------------------

template <int MODE>
__global__ __launch_bounds__(256, 2) void gemm_mfma(
    const unsigned short* __restrict__ Ahi, const unsigned short* __restrict__ Alo,
    const unsigned short* __restrict__ BThi, const unsigned short* __restrict__ BTlo,
    const float* __restrict__ bias, void* __restrict__ Cout, int M) {
    __shared__ __align__(16) unsigned short as_hi[128][40];
    __shared__ __align__(16) unsigned short as_lo[128][40];
    __shared__ __align__(16) unsigned short bs_hi[128][40];
    __shared__ __align__(16) unsigned short bs_lo[128][40];

    const int t = threadIdx.x;
    const int m0 = blockIdx.x * 128;
    const int n0 = blockIdx.y * 128;
    const int w = t >> 6, lane = t & 63;
    const int wr = (w >> 1) * 64, wc = (w & 1) * 64;
    const int lr = lane & 15;
    const int k8 = (lane >> 4) * 8;

    // staging: thread covers rows sr0 and sr0+64, one 16B (8 bf16) chunk each
    const int sr0 = t >> 2;
    const int sp = (t & 3) * 8;
    const int r0 = m0 + sr0, r1 = m0 + 64 + sr0;
    const bool v0 = (r0 < M), v1 = (r1 < M);
    const int bn0 = n0 + sr0, bn1 = n0 + 64 + sr0;

    const bf16x8 z = {0, 0, 0, 0, 0, 0, 0, 0};
    f32x4 acc[4][4];
#pragma unroll
    for (int i = 0; i < 4; ++i)
#pragma unroll
        for (int j = 0; j < 4; ++j) acc[i][j] = (f32x4){0.f, 0.f, 0.f, 0.f};

    for (int k0 = 0; k0 < 256; k0 += 32) {
        bf16x8 a0h = v0 ? *(const bf16x8*)&Ahi[(size_t)r0 * 256 + k0 + sp] : z;
        bf16x8 a1h = v1 ? *(const bf16x8*)&Ahi[(size_t)r1 * 256 + k0 + sp] : z;
        bf16x8 a0l = v0 ? *(const bf16x8*)&Alo[(size_t)r0 * 256 + k0 + sp] : z;
        bf16x8 a1l = v1 ? *(const bf16x8*)&Alo[(size_t)r1 * 256 + k0 + sp] : z;
        bf16x8 b0h = *(const bf16x8*)&BThi[(size_t)bn0 * 256 + k0 + sp];
        bf16x8 b1h = *(const bf16x8*)&BThi[(size_t)bn1 * 256 + k0 + sp];
        bf16x8 b0l = *(const bf16x8*)&BTlo[(size_t)bn0 * 256 + k0 + sp];
        bf16x8 b1l = *(const bf16x8*)&BTlo[(size_t)bn1 * 256 + k0 + sp];

        *(bf16x8*)&as_hi[sr0][sp] = a0h;
        *(bf16x8*)&as_hi[64 + sr0][sp] = a1h;
        *(bf16x8*)&as_lo[sr0][sp] = a0l;
        *(bf16x8*)&as_lo[64 + sr0][sp] = a1l;
        *(bf16x8*)&bs_hi[sr0][sp] = b0h;
        *(bf16x8*)&bs_hi[64 + sr0][sp] = b1h;
        *(bf16x8*)&bs_lo[sr0][sp] = b0l;
        *(bf16x8*)&bs_lo[64 + sr0][sp] = b1l;

        __syncthreads();

        bf16x8 ah[4], al[4], bh[4], bl[4];
#pragma unroll
        for (int i = 0; i < 4; ++i) {
            ah[i] = *(const bf16x8*)&as_hi[wr + i * 16 + lr][k8];
            al[i] = *(const bf16x8*)&as_lo[wr + i * 16 + lr][k8];
            bh[i] = *(const bf16x8*)&bs_hi[wc + i * 16 + lr][k8];
            bl[i] = *(const bf16x8*)&bs_lo[wc + i * 16 + lr][k8];
        }
#pragma unroll
        for (int mi = 0; mi < 4; ++mi)
#pragma unroll
            for (int ni = 0; ni < 4; ++ni) {
                acc[mi][ni] = mfma_bf16(ah[mi], bh[ni], acc[mi][ni]);
                acc[mi][ni] = mfma_bf16(al[mi], bh[ni], acc[mi][ni]);
                acc[mi][ni] = mfma_bf16(ah[mi], bl[ni], acc[mi][ni]);
            }
        __syncthreads();
    }

    // epilogue: D row = 4*(lane>>4)+reg, col = lane&15  [m89-verified]
    const int rbase = m0 + wr + 4 * (lane >> 4);
#pragma unroll
    for (int ni = 0; ni < 4; ++ni) {
        const int col = n0 + wc + ni * 16 + lr;
        float bcol = (MODE == 1) ? bias[col] : 0.f;
#pragma unroll
        for (int mi = 0; mi < 4; ++mi) {
#pragma unroll
            for (int r = 0; r < 4; ++r) {
                int row = rbase + mi * 16 + r;
                if (row < M) {
                    if (MODE == 0)
                        ((unsigned short*)Cout)[(size_t)row * 256 + col] = f2bf(acc[mi][ni][r]);
                    else
                        ((float*)Cout)[(size_t)row * 256 + col] = acc[mi][ni][r] + bcol;
                }
            }
        }
    }
}

// ---------------------------------------------------------------------------
// Aggregation: h[v,:] = relu(sum_e w_e * xt_bf16[src_e,:] + bias), written as
// hi/lo bf16 split (next GEMM's A operand). One block per node, lane = feature.
// ---------------------------------------------------------------------------

__global__ __launch_bounds__(256) void agg_split_kernel(const unsigned short* __restrict__ xt,
                                                        const int* __restrict__ row_ptr,
                                                        const int* __restrict__ csr_src,
                                                        const float* __restrict__ csr_w,
                                                        const float* __restrict__ bias,
                                                        unsigned short* __restrict__ Ahi,
                                                        unsigned short* __restrict__ Alo) {
    int v = blockIdx.x;
    int d = threadIdx.x;
    int s0 = row_ptr[v];
    int s1 = row_ptr[v + 1];
    float acc = 0.f;
    for (int i = s0; i < s1; ++i) {
        int s = csr_src[i];
        float w = csr_w[i];
        acc += bf2f(xt[(size_t)s * 256 + d]) * w;
    }
    float r = acc + bias[d];
    r = r > 0.f ? r : 0.f;
    unsigned short h = f2bf(r);
    Ahi[(size_t)v * 256 + d] = h;
    Alo[(size_t)v * 256 + d] = f2bf(r - bf2f(h));
}

// ---------------------------------------------------------------------------

extern "C" void kernel_launch(void* const* d_in, const int* in_sizes, int n_in,
                              void* d_out, int out_size, void* d_ws, size_t ws_size,
                              hipStream_t stream) {
    (void)in_sizes; (void)n_in; (void)out_size; (void)ws_size;
    const float* h5 = (const float*)d_in[0];
    const int*   ei = (const int*)d_in[1];
    const float* ew = (const float*)d_in[2];
    const float* W6 = (const float*)d_in[3];
    const float* b6 = (const float*)d_in[4];
    const float* W7 = (const float*)d_in[5];
    const float* b7 = (const float*)d_in[6];
    const float* Wp = (const float*)d_in[7];
    const float* bp = (const float*)d_in[8];
    float* out = (float*)d_out;

    char* ws = (char*)d_ws;
    size_t off = 0;
    auto alloc = [&](size_t bytes) -> void* {
        void* p = ws + off;
        off = (off + bytes + 255) & ~(size_t)255;
        return p;
    };

    float* deg_out = (float*)alloc(N_NODES * 4);
    float* deg_in  = (float*)alloc(N_NODES * 4);
    int*   cnt     = (int*)alloc(N_NODES * 4);
    int*   row_ptr = (int*)alloc((N_NODES + 1) * 4);
    float* nrm     = (float*)alloc(N_EDGES * 4);
    int*   csr_src = (int*)alloc(N_EDGES * 4);
    float* csr_w   = (float*)alloc(N_EDGES * 4);
    unsigned short* wt_hi = (unsigned short*)alloc(3 * 65536 * 2);
    unsigned short* wt_lo = (unsigned short*)alloc(3 * 65536 * 2);
    unsigned short* Ahi = (unsigned short*)alloc((size_t)N_NODES * 256 * 2);
    unsigned short* Alo = (unsigned short*)alloc((size_t)N_NODES * 256 * 2);
    unsigned short* xt  = (unsigned short*)alloc((size_t)N_NODES * 256 * 2);

    const int EB = (N_EDGES + 255) / 256;
    dim3 ggrid((N_NODES + 127) / 128, 2);

    hipMemsetAsync(deg_out, 0, N_NODES * 4, stream);
    hipMemsetAsync(deg_in, 0, N_NODES * 4, stream);
    hipMemsetAsync(cnt, 0, N_NODES * 4, stream);

    deg_kernel<<<EB, 256, 0, stream>>>(ei, ew, deg_out, deg_in, cnt);
    norm_kernel<<<EB, 256, 0, stream>>>(ei, ew, deg_out, deg_in, nrm);
    scan_kernel<<<1, 1024, 0, stream>>>(cnt, row_ptr);
    hipMemsetAsync(cnt, 0, N_NODES * 4, stream);
    fill_kernel<<<EB, 256, 0, stream>>>(ei, nrm, row_ptr, cnt, csr_src, csr_w);

    // input splits
    asplit_kernel<<<(N_NODES * 256 / 4 + 255) / 256, 256, 0, stream>>>(h5, Ahi, Alo);
    wsplit_kernel<<<dim3(256, 3), 256, 0, stream>>>(W6, W7, Wp, wt_hi, wt_lo);

    // layer 1
    gemm_mfma<0><<<ggrid, 256, 0, stream>>>(Ahi, Alo, wt_hi, wt_lo, nullptr, xt, N_NODES);
    agg_split_kernel<<<N_NODES, 256, 0, stream>>>(xt, row_ptr, csr_src, csr_w, b6, Ahi, Alo);

    // layer 2
    gemm_mfma<0><<<ggrid, 256, 0, stream>>>(Ahi, Alo, wt_hi + 65536, wt_lo + 65536,
                                            nullptr, xt, N_NODES);
    agg_split_kernel<<<N_NODES, 256, 0, stream>>>(xt, row_ptr, csr_src, csr_w, b7, Ahi, Alo);

    // head
    gemm_mfma<1><<<ggrid, 256, 0, stream>>>(Ahi, Alo, wt_hi + 2 * 65536, wt_lo + 2 * 65536,
                                            bp, out, N_NODES);
}

// Round 3
// 350.874 us; speedup vs baseline: 1.7020x; 1.2746x over previous
//
#include <hip/hip_runtime.h>

#define N_NODES 50000
#define N_EDGES 300000
#define DFEAT 256
#define EPS_F 1e-12f

typedef short bf16x8 __attribute__((ext_vector_type(8)));
typedef float f32x4 __attribute__((ext_vector_type(4)));

__device__ inline unsigned short f2bf(float f) {
    unsigned int u = __float_as_uint(f);
    u += 0x7FFFu + ((u >> 16) & 1u);   // round to nearest even
    return (unsigned short)(u >> 16);
}
__device__ inline float bf2f(unsigned short h) {
    return __uint_as_float(((unsigned int)h) << 16);
}

static __device__ inline f32x4 mfma_bf16(bf16x8 a, bf16x8 b, f32x4 c) {
    return __builtin_amdgcn_mfma_f32_16x16x32_bf16(a, b, c, 0, 0, 0);
}

// ---------------------------------------------------------------------------
// Graph preprocessing
// ---------------------------------------------------------------------------

__global__ void deg_kernel(const int* __restrict__ ei, const float* __restrict__ ew,
                           float* __restrict__ deg_out, float* __restrict__ deg_in,
                           int* __restrict__ cnt) {
    int e = blockIdx.x * blockDim.x + threadIdx.x;
    if (e >= N_EDGES) return;
    int s = ei[e];
    int d = ei[N_EDGES + e];
    float w = ew[e];
    atomicAdd(&deg_out[s], w);
    atomicAdd(&deg_in[d], w);
    atomicAdd(&cnt[d], 1);
}

__global__ void norm_kernel(const int* __restrict__ ei, const float* __restrict__ ew,
                            const float* __restrict__ deg_out, const float* __restrict__ deg_in,
                            float* __restrict__ nrm) {
    int e = blockIdx.x * blockDim.x + threadIdx.x;
    if (e >= N_EDGES) return;
    int s = ei[e];
    int d = ei[N_EDGES + e];
    nrm[e] = ew[e] * rsqrtf(deg_out[s] * deg_in[d] + EPS_F);
}

// Chunked single-block exclusive scan: 49 serial elems/thread + one block scan.
__global__ void scan_kernel(const int* __restrict__ cnt, int* __restrict__ row_ptr) {
    __shared__ int sh[1024];
    const int CH = (N_NODES + 1023) / 1024;  // 49
    int t = threadIdx.x;
    int b = t * CH;
    int e = b + CH < N_NODES ? b + CH : N_NODES;
    int s = 0;
    for (int i = b; i < e; ++i) s += cnt[i];
    sh[t] = s;
    __syncthreads();
    for (int off = 1; off < 1024; off <<= 1) {
        int val = (t >= off) ? sh[t - off] : 0;
        __syncthreads();
        sh[t] += val;
        __syncthreads();
    }
    int run = sh[t] - s;  // exclusive prefix of this chunk
    for (int i = b; i < e; ++i) { row_ptr[i] = run; run += cnt[i]; }
    if (t == 1023) row_ptr[N_NODES] = sh[1023];
}

__global__ void fill_kernel(const int* __restrict__ ei, const float* __restrict__ nrm,
                            const int* __restrict__ row_ptr, int* __restrict__ cur,
                            int* __restrict__ csr_src, float* __restrict__ csr_w) {
    int e = blockIdx.x * blockDim.x + threadIdx.x;
    if (e >= N_EDGES) return;
    int d = ei[N_EDGES + e];
    int pos = atomicAdd(&cur[d], 1);
    int slot = row_ptr[d] + pos;
    csr_src[slot] = ei[e];
    csr_w[slot] = nrm[e];
}

// ---------------------------------------------------------------------------
// hi/lo bf16 split of inputs
// ---------------------------------------------------------------------------

__global__ __launch_bounds__(256) void asplit_kernel(const float* __restrict__ X,
                                                     unsigned short* __restrict__ Ahi,
                                                     unsigned short* __restrict__ Alo) {
    size_t id = (size_t)(blockIdx.x * 256 + threadIdx.x) * 4;
    float4 v = *(const float4*)&X[id];
    ushort4 h, l;
    h.x = f2bf(v.x); l.x = f2bf(v.x - bf2f(h.x));
    h.y = f2bf(v.y); l.y = f2bf(v.y - bf2f(h.y));
    h.z = f2bf(v.z); l.z = f2bf(v.z - bf2f(h.z));
    h.w = f2bf(v.w); l.w = f2bf(v.w - bf2f(h.w));
    *(ushort4*)&Ahi[id] = h;
    *(ushort4*)&Alo[id] = l;
}

// W [256,256] fp32 -> transposed hi/lo bf16 BT[n][k]; grid.y selects weight
__global__ __launch_bounds__(256) void wsplit_kernel(const float* __restrict__ W6,
                                                     const float* __restrict__ W7,
                                                     const float* __restrict__ Wp,
                                                     unsigned short* __restrict__ wt_hi,
                                                     unsigned short* __restrict__ wt_lo) {
    int id = blockIdx.x * 256 + threadIdx.x;  // 0..65535
    int wsel = blockIdx.y;
    const float* W = (wsel == 0) ? W6 : (wsel == 1) ? W7 : Wp;
    int n = id & 255, k = id >> 8;
    float v = W[k * 256 + n];
    unsigned short h = f2bf(v);
    wt_hi[(size_t)wsel * 65536 + n * 256 + k] = h;
    wt_lo[(size_t)wsel * 65536 + n * 256 + k] = f2bf(v - bf2f(h));
}

// ---------------------------------------------------------------------------
// MFMA GEMM (bf16x3): 128x128 tile, 4 waves, 64x64/wave, BK=32
// ---------------------------------------------------------------------------

template <int MODE>
__global__ __launch_bounds__(256, 2) void gemm_mfma(
    const unsigned short* __restrict__ Ahi, const unsigned short* __restrict__ Alo,
    const unsigned short* __restrict__ BThi, const unsigned short* __restrict__ BTlo,
    const float* __restrict__ bias, void* __restrict__ Cout, int M) {
    __shared__ __align__(16) unsigned short as_hi[128][40];
    __shared__ __align__(16) unsigned short as_lo[128][40];
    __shared__ __align__(16) unsigned short bs_hi[128][40];
    __shared__ __align__(16) unsigned short bs_lo[128][40];

    const int t = threadIdx.x;
    const int m0 = blockIdx.x * 128;
    const int n0 = blockIdx.y * 128;
    const int w = t >> 6, lane = t & 63;
    const int wr = (w >> 1) * 64, wc = (w & 1) * 64;
    const int lr = lane & 15;
    const int k8 = (lane >> 4) * 8;

    const int sr0 = t >> 2;
    const int sp = (t & 3) * 8;
    const int r0 = m0 + sr0, r1 = m0 + 64 + sr0;
    const bool v0 = (r0 < M), v1 = (r1 < M);
    const int bn0 = n0 + sr0, bn1 = n0 + 64 + sr0;

    const bf16x8 z = {0, 0, 0, 0, 0, 0, 0, 0};
    f32x4 acc[4][4];
#pragma unroll
    for (int i = 0; i < 4; ++i)
#pragma unroll
        for (int j = 0; j < 4; ++j) acc[i][j] = (f32x4){0.f, 0.f, 0.f, 0.f};

    for (int k0 = 0; k0 < 256; k0 += 32) {
        bf16x8 a0h = v0 ? *(const bf16x8*)&Ahi[(size_t)r0 * 256 + k0 + sp] : z;
        bf16x8 a1h = v1 ? *(const bf16x8*)&Ahi[(size_t)r1 * 256 + k0 + sp] : z;
        bf16x8 a0l = v0 ? *(const bf16x8*)&Alo[(size_t)r0 * 256 + k0 + sp] : z;
        bf16x8 a1l = v1 ? *(const bf16x8*)&Alo[(size_t)r1 * 256 + k0 + sp] : z;
        bf16x8 b0h = *(const bf16x8*)&BThi[(size_t)bn0 * 256 + k0 + sp];
        bf16x8 b1h = *(const bf16x8*)&BThi[(size_t)bn1 * 256 + k0 + sp];
        bf16x8 b0l = *(const bf16x8*)&BTlo[(size_t)bn0 * 256 + k0 + sp];
        bf16x8 b1l = *(const bf16x8*)&BTlo[(size_t)bn1 * 256 + k0 + sp];

        *(bf16x8*)&as_hi[sr0][sp] = a0h;
        *(bf16x8*)&as_hi[64 + sr0][sp] = a1h;
        *(bf16x8*)&as_lo[sr0][sp] = a0l;
        *(bf16x8*)&as_lo[64 + sr0][sp] = a1l;
        *(bf16x8*)&bs_hi[sr0][sp] = b0h;
        *(bf16x8*)&bs_hi[64 + sr0][sp] = b1h;
        *(bf16x8*)&bs_lo[sr0][sp] = b0l;
        *(bf16x8*)&bs_lo[64 + sr0][sp] = b1l;

        __syncthreads();

        bf16x8 ah[4], al[4], bh[4], bl[4];
#pragma unroll
        for (int i = 0; i < 4; ++i) {
            ah[i] = *(const bf16x8*)&as_hi[wr + i * 16 + lr][k8];
            al[i] = *(const bf16x8*)&as_lo[wr + i * 16 + lr][k8];
            bh[i] = *(const bf16x8*)&bs_hi[wc + i * 16 + lr][k8];
            bl[i] = *(const bf16x8*)&bs_lo[wc + i * 16 + lr][k8];
        }
#pragma unroll
        for (int mi = 0; mi < 4; ++mi)
#pragma unroll
            for (int ni = 0; ni < 4; ++ni) {
                acc[mi][ni] = mfma_bf16(ah[mi], bh[ni], acc[mi][ni]);
                acc[mi][ni] = mfma_bf16(al[mi], bh[ni], acc[mi][ni]);
                acc[mi][ni] = mfma_bf16(ah[mi], bl[ni], acc[mi][ni]);
            }
        __syncthreads();
    }

    // epilogue: D row = 4*(lane>>4)+reg, col = lane&15  [m89-verified]
    const int rbase = m0 + wr + 4 * (lane >> 4);
#pragma unroll
    for (int ni = 0; ni < 4; ++ni) {
        const int col = n0 + wc + ni * 16 + lr;
        float bcol = (MODE == 1) ? bias[col] : 0.f;
#pragma unroll
        for (int mi = 0; mi < 4; ++mi) {
#pragma unroll
            for (int r = 0; r < 4; ++r) {
                int row = rbase + mi * 16 + r;
                if (row < M) {
                    if (MODE == 0)
                        ((unsigned short*)Cout)[(size_t)row * 256 + col] = f2bf(acc[mi][ni][r]);
                    else
                        ((float*)Cout)[(size_t)row * 256 + col] = acc[mi][ni][r] + bcol;
                }
            }
        }
    }
}

// ---------------------------------------------------------------------------
// Aggregation v2: 8 nodes/block, 32 lanes/node, 8 features/lane (bf16x8).
// Batch 4 edges: load indices/weights first, then 4 independent 16B gathers.
// ---------------------------------------------------------------------------

__global__ __launch_bounds__(256) void agg_split_kernel(const unsigned short* __restrict__ xt,
                                                        const int* __restrict__ row_ptr,
                                                        const int* __restrict__ csr_src,
                                                        const float* __restrict__ csr_w,
                                                        const float* __restrict__ bias,
                                                        unsigned short* __restrict__ Ahi,
                                                        unsigned short* __restrict__ Alo) {
    const int g = threadIdx.x >> 5;           // node slot 0..7
    const int l = threadIdx.x & 31;           // lane within node group
    const int v = blockIdx.x * 8 + g;
    const int d0 = l * 8;                     // this lane's 8 features

    const int s0 = row_ptr[v];
    const int s1 = row_ptr[v + 1];

    float acc[8] = {0.f, 0.f, 0.f, 0.f, 0.f, 0.f, 0.f, 0.f};

    int i = s0;
    for (; i + 4 <= s1; i += 4) {
        int   src[4];
        float wv[4];
#pragma unroll
        for (int u = 0; u < 4; ++u) { src[u] = csr_src[i + u]; wv[u] = csr_w[i + u]; }
        bf16x8 val[4];
#pragma unroll
        for (int u = 0; u < 4; ++u)
            val[u] = *(const bf16x8*)&xt[(size_t)src[u] * 256 + d0];
#pragma unroll
        for (int u = 0; u < 4; ++u)
#pragma unroll
            for (int j = 0; j < 8; ++j)
                acc[j] += bf2f((unsigned short)val[u][j]) * wv[u];
    }
    // remainder (0..3 edges), keep loads independent too
    {
        int rem = s1 - i;
        int   src[3];
        float wv[3];
#pragma unroll
        for (int u = 0; u < 3; ++u) {
            src[u] = (u < rem) ? csr_src[i + u] : 0;
            wv[u]  = (u < rem) ? csr_w[i + u] : 0.f;
        }
        bf16x8 val[3];
#pragma unroll
        for (int u = 0; u < 3; ++u)
            val[u] = *(const bf16x8*)&xt[(size_t)src[u] * 256 + d0];
#pragma unroll
        for (int u = 0; u < 3; ++u)
#pragma unroll
            for (int j = 0; j < 8; ++j)
                acc[j] += bf2f((unsigned short)val[u][j]) * wv[u];
    }

    bf16x8 ho, lo;
#pragma unroll
    for (int j = 0; j < 8; ++j) {
        float r = acc[j] + bias[d0 + j];
        r = r > 0.f ? r : 0.f;
        unsigned short h = f2bf(r);
        ho[j] = (short)h;
        lo[j] = (short)f2bf(r - bf2f(h));
    }
    *(bf16x8*)&Ahi[(size_t)v * 256 + d0] = ho;
    *(bf16x8*)&Alo[(size_t)v * 256 + d0] = lo;
}

// ---------------------------------------------------------------------------

extern "C" void kernel_launch(void* const* d_in, const int* in_sizes, int n_in,
                              void* d_out, int out_size, void* d_ws, size_t ws_size,
                              hipStream_t stream) {
    (void)in_sizes; (void)n_in; (void)out_size; (void)ws_size;
    const float* h5 = (const float*)d_in[0];
    const int*   ei = (const int*)d_in[1];
    const float* ew = (const float*)d_in[2];
    const float* W6 = (const float*)d_in[3];
    const float* b6 = (const float*)d_in[4];
    const float* W7 = (const float*)d_in[5];
    const float* b7 = (const float*)d_in[6];
    const float* Wp = (const float*)d_in[7];
    const float* bp = (const float*)d_in[8];
    float* out = (float*)d_out;

    char* ws = (char*)d_ws;
    size_t off = 0;
    auto alloc = [&](size_t bytes) -> void* {
        void* p = ws + off;
        off = (off + bytes + 255) & ~(size_t)255;
        return p;
    };

    float* deg_out = (float*)alloc(N_NODES * 4);
    float* deg_in  = (float*)alloc(N_NODES * 4);
    int*   cnt     = (int*)alloc(N_NODES * 4);
    int*   row_ptr = (int*)alloc((N_NODES + 1) * 4);
    float* nrm     = (float*)alloc(N_EDGES * 4);
    int*   csr_src = (int*)alloc(N_EDGES * 4);
    float* csr_w   = (float*)alloc(N_EDGES * 4);
    unsigned short* wt_hi = (unsigned short*)alloc(3 * 65536 * 2);
    unsigned short* wt_lo = (unsigned short*)alloc(3 * 65536 * 2);
    unsigned short* Ahi = (unsigned short*)alloc((size_t)N_NODES * 256 * 2);
    unsigned short* Alo = (unsigned short*)alloc((size_t)N_NODES * 256 * 2);
    unsigned short* xt  = (unsigned short*)alloc((size_t)N_NODES * 256 * 2);

    const int EB = (N_EDGES + 255) / 256;
    dim3 ggrid((N_NODES + 127) / 128, 2);

    hipMemsetAsync(deg_out, 0, N_NODES * 4, stream);
    hipMemsetAsync(deg_in, 0, N_NODES * 4, stream);
    hipMemsetAsync(cnt, 0, N_NODES * 4, stream);

    deg_kernel<<<EB, 256, 0, stream>>>(ei, ew, deg_out, deg_in, cnt);
    norm_kernel<<<EB, 256, 0, stream>>>(ei, ew, deg_out, deg_in, nrm);
    scan_kernel<<<1, 1024, 0, stream>>>(cnt, row_ptr);
    hipMemsetAsync(cnt, 0, N_NODES * 4, stream);
    fill_kernel<<<EB, 256, 0, stream>>>(ei, nrm, row_ptr, cnt, csr_src, csr_w);

    // input splits
    asplit_kernel<<<(N_NODES * 256 / 4 + 255) / 256, 256, 0, stream>>>(h5, Ahi, Alo);
    wsplit_kernel<<<dim3(256, 3), 256, 0, stream>>>(W6, W7, Wp, wt_hi, wt_lo);

    // layer 1
    gemm_mfma<0><<<ggrid, 256, 0, stream>>>(Ahi, Alo, wt_hi, wt_lo, nullptr, xt, N_NODES);
    agg_split_kernel<<<(N_NODES + 7) / 8, 256, 0, stream>>>(xt, row_ptr, csr_src, csr_w, b6, Ahi, Alo);

    // layer 2
    gemm_mfma<0><<<ggrid, 256, 0, stream>>>(Ahi, Alo, wt_hi + 65536, wt_lo + 65536,
                                            nullptr, xt, N_NODES);
    agg_split_kernel<<<(N_NODES + 7) / 8, 256, 0, stream>>>(xt, row_ptr, csr_src, csr_w, b7, Ahi, Alo);

    // head
    gemm_mfma<1><<<ggrid, 256, 0, stream>>>(Ahi, Alo, wt_hi + 2 * 65536, wt_lo + 2 * 65536,
                                            bp, out, N_NODES);
}

// Round 4
// 285.854 us; speedup vs baseline: 2.0892x; 1.2275x over previous
//
#include <hip/hip_runtime.h>

#define N_NODES 50000
#define N_EDGES 300000
#define DFEAT 256
#define EPS_F 1e-12f
#define SCAN_NB ((N_NODES + 255) / 256)   // 196

typedef short bf16x8 __attribute__((ext_vector_type(8)));
typedef float f32x4 __attribute__((ext_vector_type(4)));

__device__ inline unsigned short f2bf(float f) {
    unsigned int u = __float_as_uint(f);
    u += 0x7FFFu + ((u >> 16) & 1u);   // round to nearest even
    return (unsigned short)(u >> 16);
}
__device__ inline float bf2f(unsigned short h) {
    return __uint_as_float(((unsigned int)h) << 16);
}

static __device__ inline f32x4 mfma_bf16(bf16x8 a, bf16x8 b, f32x4 c) {
    return __builtin_amdgcn_mfma_f32_16x16x32_bf16(a, b, c, 0, 0, 0);
}

// ---------------------------------------------------------------------------
// Graph preprocessing
// ---------------------------------------------------------------------------

__global__ void deg_kernel(const int* __restrict__ ei, const float* __restrict__ ew,
                           float* __restrict__ deg_out, float* __restrict__ deg_in,
                           int* __restrict__ cnt) {
    int e = blockIdx.x * blockDim.x + threadIdx.x;
    if (e >= N_EDGES) return;
    int s = ei[e];
    int d = ei[N_EDGES + e];
    float w = ew[e];
    atomicAdd(&deg_out[s], w);
    atomicAdd(&deg_in[d], w);
    atomicAdd(&cnt[d], 1);
}

__global__ void norm_kernel(const int* __restrict__ ei, const float* __restrict__ ew,
                            const float* __restrict__ deg_out, const float* __restrict__ deg_in,
                            float* __restrict__ nrm) {
    int e = blockIdx.x * blockDim.x + threadIdx.x;
    if (e >= N_EDGES) return;
    int s = ei[e];
    int d = ei[N_EDGES + e];
    nrm[e] = ew[e] * rsqrtf(deg_out[s] * deg_in[d] + EPS_F);
}

// --- 3-kernel decomposed exclusive scan of cnt -> row_ptr -------------------

__global__ __launch_bounds__(256) void scan1_kernel(const int* __restrict__ cnt,
                                                    int* __restrict__ partial) {
    __shared__ int sh[256];
    int i = blockIdx.x * 256 + threadIdx.x;
    int v = (i < N_NODES) ? cnt[i] : 0;
    sh[threadIdx.x] = v;
    __syncthreads();
    for (int off = 128; off > 0; off >>= 1) {
        if (threadIdx.x < (unsigned)off) sh[threadIdx.x] += sh[threadIdx.x + off];
        __syncthreads();
    }
    if (threadIdx.x == 0) partial[blockIdx.x] = sh[0];
}

__global__ __launch_bounds__(256) void scan2_kernel(int* __restrict__ partial) {
    __shared__ int sh[256];
    int t = threadIdx.x;
    int v = (t < SCAN_NB) ? partial[t] : 0;
    sh[t] = v;
    __syncthreads();
    for (int off = 1; off < 256; off <<= 1) {
        int x = (t >= off) ? sh[t - off] : 0;
        __syncthreads();
        sh[t] += x;
        __syncthreads();
    }
    if (t < SCAN_NB) partial[t] = sh[t] - v;  // exclusive
}

__global__ __launch_bounds__(256) void scan3_kernel(const int* __restrict__ cnt,
                                                    const int* __restrict__ partial,
                                                    int* __restrict__ row_ptr) {
    __shared__ int sh[256];
    int t = threadIdx.x;
    int i = blockIdx.x * 256 + t;
    int v = (i < N_NODES) ? cnt[i] : 0;
    sh[t] = v;
    __syncthreads();
    for (int off = 1; off < 256; off <<= 1) {
        int x = (t >= off) ? sh[t - off] : 0;
        __syncthreads();
        sh[t] += x;
        __syncthreads();
    }
    if (i < N_NODES) row_ptr[i] = sh[t] - v + partial[blockIdx.x];
    if (i == 0) row_ptr[N_NODES] = N_EDGES;  // total is a known constant
}

__global__ void fill_kernel(const int* __restrict__ ei, const float* __restrict__ nrm,
                            const int* __restrict__ row_ptr, int* __restrict__ cur,
                            int* __restrict__ csr_src, float* __restrict__ csr_w) {
    int e = blockIdx.x * blockDim.x + threadIdx.x;
    if (e >= N_EDGES) return;
    int d = ei[N_EDGES + e];
    int pos = atomicAdd(&cur[d], 1);
    int slot = row_ptr[d] + pos;
    csr_src[slot] = ei[e];
    csr_w[slot] = nrm[e];
}

// ---------------------------------------------------------------------------
// hi/lo bf16 split of inputs
// ---------------------------------------------------------------------------

__global__ __launch_bounds__(256) void asplit_kernel(const float* __restrict__ X,
                                                     unsigned short* __restrict__ Ahi,
                                                     unsigned short* __restrict__ Alo) {
    size_t id = (size_t)(blockIdx.x * 256 + threadIdx.x) * 4;
    float4 v = *(const float4*)&X[id];
    ushort4 h, l;
    h.x = f2bf(v.x); l.x = f2bf(v.x - bf2f(h.x));
    h.y = f2bf(v.y); l.y = f2bf(v.y - bf2f(h.y));
    h.z = f2bf(v.z); l.z = f2bf(v.z - bf2f(h.z));
    h.w = f2bf(v.w); l.w = f2bf(v.w - bf2f(h.w));
    *(ushort4*)&Ahi[id] = h;
    *(ushort4*)&Alo[id] = l;
}

// W [256,256] fp32 -> transposed hi/lo bf16 BT[n][k]; grid.y selects weight
__global__ __launch_bounds__(256) void wsplit_kernel(const float* __restrict__ W6,
                                                     const float* __restrict__ W7,
                                                     const float* __restrict__ Wp,
                                                     unsigned short* __restrict__ wt_hi,
                                                     unsigned short* __restrict__ wt_lo) {
    int id = blockIdx.x * 256 + threadIdx.x;  // 0..65535
    int wsel = blockIdx.y;
    const float* W = (wsel == 0) ? W6 : (wsel == 1) ? W7 : Wp;
    int n = id & 255, k = id >> 8;
    float v = W[k * 256 + n];
    unsigned short h = f2bf(v);
    wt_hi[(size_t)wsel * 65536 + n * 256 + k] = h;
    wt_lo[(size_t)wsel * 65536 + n * 256 + k] = f2bf(v - bf2f(h));
}

// ---------------------------------------------------------------------------
// MFMA GEMM (bf16x3): 128x128 tile, 4 waves, 64x64/wave, BK=32
// ---------------------------------------------------------------------------

template <int MODE>
__global__ __launch_bounds__(256, 2) void gemm_mfma(
    const unsigned short* __restrict__ Ahi, const unsigned short* __restrict__ Alo,
    const unsigned short* __restrict__ BThi, const unsigned short* __restrict__ BTlo,
    const float* __restrict__ bias, void* __restrict__ Cout, int M) {
    __shared__ __align__(16) unsigned short as_hi[128][40];
    __shared__ __align__(16) unsigned short as_lo[128][40];
    __shared__ __align__(16) unsigned short bs_hi[128][40];
    __shared__ __align__(16) unsigned short bs_lo[128][40];

    const int t = threadIdx.x;
    const int m0 = blockIdx.x * 128;
    const int n0 = blockIdx.y * 128;
    const int w = t >> 6, lane = t & 63;
    const int wr = (w >> 1) * 64, wc = (w & 1) * 64;
    const int lr = lane & 15;
    const int k8 = (lane >> 4) * 8;

    const int sr0 = t >> 2;
    const int sp = (t & 3) * 8;
    const int r0 = m0 + sr0, r1 = m0 + 64 + sr0;
    const bool v0 = (r0 < M), v1 = (r1 < M);
    const int bn0 = n0 + sr0, bn1 = n0 + 64 + sr0;

    const bf16x8 z = {0, 0, 0, 0, 0, 0, 0, 0};
    f32x4 acc[4][4];
#pragma unroll
    for (int i = 0; i < 4; ++i)
#pragma unroll
        for (int j = 0; j < 4; ++j) acc[i][j] = (f32x4){0.f, 0.f, 0.f, 0.f};

    for (int k0 = 0; k0 < 256; k0 += 32) {
        bf16x8 a0h = v0 ? *(const bf16x8*)&Ahi[(size_t)r0 * 256 + k0 + sp] : z;
        bf16x8 a1h = v1 ? *(const bf16x8*)&Ahi[(size_t)r1 * 256 + k0 + sp] : z;
        bf16x8 a0l = v0 ? *(const bf16x8*)&Alo[(size_t)r0 * 256 + k0 + sp] : z;
        bf16x8 a1l = v1 ? *(const bf16x8*)&Alo[(size_t)r1 * 256 + k0 + sp] : z;
        bf16x8 b0h = *(const bf16x8*)&BThi[(size_t)bn0 * 256 + k0 + sp];
        bf16x8 b1h = *(const bf16x8*)&BThi[(size_t)bn1 * 256 + k0 + sp];
        bf16x8 b0l = *(const bf16x8*)&BTlo[(size_t)bn0 * 256 + k0 + sp];
        bf16x8 b1l = *(const bf16x8*)&BTlo[(size_t)bn1 * 256 + k0 + sp];

        *(bf16x8*)&as_hi[sr0][sp] = a0h;
        *(bf16x8*)&as_hi[64 + sr0][sp] = a1h;
        *(bf16x8*)&as_lo[sr0][sp] = a0l;
        *(bf16x8*)&as_lo[64 + sr0][sp] = a1l;
        *(bf16x8*)&bs_hi[sr0][sp] = b0h;
        *(bf16x8*)&bs_hi[64 + sr0][sp] = b1h;
        *(bf16x8*)&bs_lo[sr0][sp] = b0l;
        *(bf16x8*)&bs_lo[64 + sr0][sp] = b1l;

        __syncthreads();

        bf16x8 ah[4], al[4], bh[4], bl[4];
#pragma unroll
        for (int i = 0; i < 4; ++i) {
            ah[i] = *(const bf16x8*)&as_hi[wr + i * 16 + lr][k8];
            al[i] = *(const bf16x8*)&as_lo[wr + i * 16 + lr][k8];
            bh[i] = *(const bf16x8*)&bs_hi[wc + i * 16 + lr][k8];
            bl[i] = *(const bf16x8*)&bs_lo[wc + i * 16 + lr][k8];
        }
#pragma unroll
        for (int mi = 0; mi < 4; ++mi)
#pragma unroll
            for (int ni = 0; ni < 4; ++ni) {
                acc[mi][ni] = mfma_bf16(ah[mi], bh[ni], acc[mi][ni]);
                acc[mi][ni] = mfma_bf16(al[mi], bh[ni], acc[mi][ni]);
                acc[mi][ni] = mfma_bf16(ah[mi], bl[ni], acc[mi][ni]);
            }
        __syncthreads();
    }

    // epilogue: D row = 4*(lane>>4)+reg, col = lane&15  [m89-verified]
    const int rbase = m0 + wr + 4 * (lane >> 4);
#pragma unroll
    for (int ni = 0; ni < 4; ++ni) {
        const int col = n0 + wc + ni * 16 + lr;
        float bcol = (MODE == 1) ? bias[col] : 0.f;
#pragma unroll
        for (int mi = 0; mi < 4; ++mi) {
#pragma unroll
            for (int r = 0; r < 4; ++r) {
                int row = rbase + mi * 16 + r;
                if (row < M) {
                    if (MODE == 0)
                        ((unsigned short*)Cout)[(size_t)row * 256 + col] = f2bf(acc[mi][ni][r]);
                    else
                        ((float*)Cout)[(size_t)row * 256 + col] = acc[mi][ni][r] + bcol;
                }
            }
        }
    }
}

// ---------------------------------------------------------------------------
// Aggregation: 8 nodes/block, 32 lanes/node, 8 features/lane (bf16x8),
// 4 independent edge gathers in flight.
// ---------------------------------------------------------------------------

__global__ __launch_bounds__(256) void agg_split_kernel(const unsigned short* __restrict__ xt,
                                                        const int* __restrict__ row_ptr,
                                                        const int* __restrict__ csr_src,
                                                        const float* __restrict__ csr_w,
                                                        const float* __restrict__ bias,
                                                        unsigned short* __restrict__ Ahi,
                                                        unsigned short* __restrict__ Alo) {
    const int g = threadIdx.x >> 5;           // node slot 0..7
    const int l = threadIdx.x & 31;           // lane within node group
    const int v = blockIdx.x * 8 + g;
    const int d0 = l * 8;                     // this lane's 8 features

    const int s0 = row_ptr[v];
    const int s1 = row_ptr[v + 1];

    float acc[8] = {0.f, 0.f, 0.f, 0.f, 0.f, 0.f, 0.f, 0.f};

    int i = s0;
    for (; i + 4 <= s1; i += 4) {
        int   src[4];
        float wv[4];
#pragma unroll
        for (int u = 0; u < 4; ++u) { src[u] = csr_src[i + u]; wv[u] = csr_w[i + u]; }
        bf16x8 val[4];
#pragma unroll
        for (int u = 0; u < 4; ++u)
            val[u] = *(const bf16x8*)&xt[(size_t)src[u] * 256 + d0];
#pragma unroll
        for (int u = 0; u < 4; ++u)
#pragma unroll
            for (int j = 0; j < 8; ++j)
                acc[j] += bf2f((unsigned short)val[u][j]) * wv[u];
    }
    {
        int rem = s1 - i;
        int   src[3];
        float wv[3];
#pragma unroll
        for (int u = 0; u < 3; ++u) {
            src[u] = (u < rem) ? csr_src[i + u] : 0;
            wv[u]  = (u < rem) ? csr_w[i + u] : 0.f;
        }
        bf16x8 val[3];
#pragma unroll
        for (int u = 0; u < 3; ++u)
            val[u] = *(const bf16x8*)&xt[(size_t)src[u] * 256 + d0];
#pragma unroll
        for (int u = 0; u < 3; ++u)
#pragma unroll
            for (int j = 0; j < 8; ++j)
                acc[j] += bf2f((unsigned short)val[u][j]) * wv[u];
    }

    bf16x8 ho, lo;
#pragma unroll
    for (int j = 0; j < 8; ++j) {
        float r = acc[j] + bias[d0 + j];
        r = r > 0.f ? r : 0.f;
        unsigned short h = f2bf(r);
        ho[j] = (short)h;
        lo[j] = (short)f2bf(r - bf2f(h));
    }
    *(bf16x8*)&Ahi[(size_t)v * 256 + d0] = ho;
    *(bf16x8*)&Alo[(size_t)v * 256 + d0] = lo;
}

// ---------------------------------------------------------------------------

extern "C" void kernel_launch(void* const* d_in, const int* in_sizes, int n_in,
                              void* d_out, int out_size, void* d_ws, size_t ws_size,
                              hipStream_t stream) {
    (void)in_sizes; (void)n_in; (void)out_size; (void)ws_size;
    const float* h5 = (const float*)d_in[0];
    const int*   ei = (const int*)d_in[1];
    const float* ew = (const float*)d_in[2];
    const float* W6 = (const float*)d_in[3];
    const float* b6 = (const float*)d_in[4];
    const float* W7 = (const float*)d_in[5];
    const float* b7 = (const float*)d_in[6];
    const float* Wp = (const float*)d_in[7];
    const float* bp = (const float*)d_in[8];
    float* out = (float*)d_out;

    char* ws = (char*)d_ws;
    size_t off = 0;
    auto alloc = [&](size_t bytes) -> void* {
        void* p = ws + off;
        off = (off + bytes + 255) & ~(size_t)255;
        return p;
    };

    float* deg_out = (float*)alloc(N_NODES * 4);
    float* deg_in  = (float*)alloc(N_NODES * 4);
    int*   cnt     = (int*)alloc(N_NODES * 4);
    int*   row_ptr = (int*)alloc((N_NODES + 1) * 4);
    int*   partial = (int*)alloc(SCAN_NB * 4);
    float* nrm     = (float*)alloc(N_EDGES * 4);
    int*   csr_src = (int*)alloc(N_EDGES * 4);
    float* csr_w   = (float*)alloc(N_EDGES * 4);
    unsigned short* wt_hi = (unsigned short*)alloc(3 * 65536 * 2);
    unsigned short* wt_lo = (unsigned short*)alloc(3 * 65536 * 2);
    unsigned short* Ahi = (unsigned short*)alloc((size_t)N_NODES * 256 * 2);
    unsigned short* Alo = (unsigned short*)alloc((size_t)N_NODES * 256 * 2);
    unsigned short* xt  = (unsigned short*)alloc((size_t)N_NODES * 256 * 2);

    const int EB = (N_EDGES + 255) / 256;
    dim3 ggrid((N_NODES + 127) / 128, 2);

    hipMemsetAsync(deg_out, 0, N_NODES * 4, stream);
    hipMemsetAsync(deg_in, 0, N_NODES * 4, stream);
    hipMemsetAsync(cnt, 0, N_NODES * 4, stream);

    deg_kernel<<<EB, 256, 0, stream>>>(ei, ew, deg_out, deg_in, cnt);
    norm_kernel<<<EB, 256, 0, stream>>>(ei, ew, deg_out, deg_in, nrm);
    scan1_kernel<<<SCAN_NB, 256, 0, stream>>>(cnt, partial);
    scan2_kernel<<<1, 256, 0, stream>>>(partial);
    scan3_kernel<<<SCAN_NB, 256, 0, stream>>>(cnt, partial, row_ptr);
    hipMemsetAsync(cnt, 0, N_NODES * 4, stream);
    fill_kernel<<<EB, 256, 0, stream>>>(ei, nrm, row_ptr, cnt, csr_src, csr_w);

    // input splits
    asplit_kernel<<<(N_NODES * 256 / 4 + 255) / 256, 256, 0, stream>>>(h5, Ahi, Alo);
    wsplit_kernel<<<dim3(256, 3), 256, 0, stream>>>(W6, W7, Wp, wt_hi, wt_lo);

    // layer 1
    gemm_mfma<0><<<ggrid, 256, 0, stream>>>(Ahi, Alo, wt_hi, wt_lo, nullptr, xt, N_NODES);
    agg_split_kernel<<<(N_NODES + 7) / 8, 256, 0, stream>>>(xt, row_ptr, csr_src, csr_w, b6, Ahi, Alo);

    // layer 2
    gemm_mfma<0><<<ggrid, 256, 0, stream>>>(Ahi, Alo, wt_hi + 65536, wt_lo + 65536,
                                            nullptr, xt, N_NODES);
    agg_split_kernel<<<(N_NODES + 7) / 8, 256, 0, stream>>>(xt, row_ptr, csr_src, csr_w, b7, Ahi, Alo);

    // head
    gemm_mfma<1><<<ggrid, 256, 0, stream>>>(Ahi, Alo, wt_hi + 2 * 65536, wt_lo + 2 * 65536,
                                            bp, out, N_NODES);
}

// Round 5
// 263.915 us; speedup vs baseline: 2.2628x; 1.0831x over previous
//
#include <hip/hip_runtime.h>

#define N_NODES 50000
#define N_PAD   50048            // padded row count (multiple of 128) for A/xt buffers
#define N_EDGES 300000
#define DFEAT 256
#define EPS_F 1e-12f
#define SCAN_NB ((N_NODES + 255) / 256)   // 196

typedef short bf16x8 __attribute__((ext_vector_type(8)));
typedef float f32x4 __attribute__((ext_vector_type(4)));

__device__ inline unsigned short f2bf(float f) {
    unsigned int u = __float_as_uint(f);
    u += 0x7FFFu + ((u >> 16) & 1u);   // round to nearest even
    return (unsigned short)(u >> 16);
}
__device__ inline float bf2f(unsigned short h) {
    return __uint_as_float(((unsigned int)h) << 16);
}

static __device__ inline f32x4 mfma_bf16(bf16x8 a, bf16x8 b, f32x4 c) {
    return __builtin_amdgcn_mfma_f32_16x16x32_bf16(a, b, c, 0, 0, 0);
}

// async global->LDS, 16B per lane; LDS dest is wave-uniform base + lane*16
__device__ inline void gl16(const unsigned short* g, unsigned short* l) {
    __builtin_amdgcn_global_load_lds(
        (const __attribute__((address_space(1))) void*)g,
        (__attribute__((address_space(3))) void*)l, 16, 0, 0);
}

// ---------------------------------------------------------------------------
// Graph preprocessing
// ---------------------------------------------------------------------------

__global__ void deg_kernel(const int* __restrict__ ei, const float* __restrict__ ew,
                           float* __restrict__ deg_out, float* __restrict__ deg_in,
                           int* __restrict__ cnt) {
    int e = blockIdx.x * blockDim.x + threadIdx.x;
    if (e >= N_EDGES) return;
    int s = ei[e];
    int d = ei[N_EDGES + e];
    float w = ew[e];
    atomicAdd(&deg_out[s], w);
    atomicAdd(&deg_in[d], w);
    atomicAdd(&cnt[d], 1);
}

__global__ void norm_kernel(const int* __restrict__ ei, const float* __restrict__ ew,
                            const float* __restrict__ deg_out, const float* __restrict__ deg_in,
                            float* __restrict__ nrm) {
    int e = blockIdx.x * blockDim.x + threadIdx.x;
    if (e >= N_EDGES) return;
    int s = ei[e];
    int d = ei[N_EDGES + e];
    nrm[e] = ew[e] * rsqrtf(deg_out[s] * deg_in[d] + EPS_F);
}

// --- 3-kernel decomposed exclusive scan of cnt -> row_ptr -------------------

__global__ __launch_bounds__(256) void scan1_kernel(const int* __restrict__ cnt,
                                                    int* __restrict__ partial) {
    __shared__ int sh[256];
    int i = blockIdx.x * 256 + threadIdx.x;
    int v = (i < N_NODES) ? cnt[i] : 0;
    sh[threadIdx.x] = v;
    __syncthreads();
    for (int off = 128; off > 0; off >>= 1) {
        if (threadIdx.x < (unsigned)off) sh[threadIdx.x] += sh[threadIdx.x + off];
        __syncthreads();
    }
    if (threadIdx.x == 0) partial[blockIdx.x] = sh[0];
}

__global__ __launch_bounds__(256) void scan2_kernel(int* __restrict__ partial) {
    __shared__ int sh[256];
    int t = threadIdx.x;
    int v = (t < SCAN_NB) ? partial[t] : 0;
    sh[t] = v;
    __syncthreads();
    for (int off = 1; off < 256; off <<= 1) {
        int x = (t >= off) ? sh[t - off] : 0;
        __syncthreads();
        sh[t] += x;
        __syncthreads();
    }
    if (t < SCAN_NB) partial[t] = sh[t] - v;  // exclusive
}

__global__ __launch_bounds__(256) void scan3_kernel(const int* __restrict__ cnt,
                                                    const int* __restrict__ partial,
                                                    int* __restrict__ row_ptr) {
    __shared__ int sh[256];
    int t = threadIdx.x;
    int i = blockIdx.x * 256 + t;
    int v = (i < N_NODES) ? cnt[i] : 0;
    sh[t] = v;
    __syncthreads();
    for (int off = 1; off < 256; off <<= 1) {
        int x = (t >= off) ? sh[t - off] : 0;
        __syncthreads();
        sh[t] += x;
        __syncthreads();
    }
    if (i < N_NODES) row_ptr[i] = sh[t] - v + partial[blockIdx.x];
    if (i == 0) row_ptr[N_NODES] = N_EDGES;  // total is a known constant
}

__global__ void fill_kernel(const int* __restrict__ ei, const float* __restrict__ nrm,
                            const int* __restrict__ row_ptr, int* __restrict__ cur,
                            int* __restrict__ csr_src, float* __restrict__ csr_w) {
    int e = blockIdx.x * blockDim.x + threadIdx.x;
    if (e >= N_EDGES) return;
    int d = ei[N_EDGES + e];
    int pos = atomicAdd(&cur[d], 1);
    int slot = row_ptr[d] + pos;
    csr_src[slot] = ei[e];
    csr_w[slot] = nrm[e];
}

// ---------------------------------------------------------------------------
// hi/lo bf16 split of inputs
// ---------------------------------------------------------------------------

__global__ __launch_bounds__(256) void asplit_kernel(const float* __restrict__ X,
                                                     unsigned short* __restrict__ Ahi,
                                                     unsigned short* __restrict__ Alo) {
    size_t id = (size_t)(blockIdx.x * 256 + threadIdx.x) * 4;
    float4 v = *(const float4*)&X[id];
    ushort4 h, l;
    h.x = f2bf(v.x); l.x = f2bf(v.x - bf2f(h.x));
    h.y = f2bf(v.y); l.y = f2bf(v.y - bf2f(h.y));
    h.z = f2bf(v.z); l.z = f2bf(v.z - bf2f(h.z));
    h.w = f2bf(v.w); l.w = f2bf(v.w - bf2f(h.w));
    *(ushort4*)&Ahi[id] = h;
    *(ushort4*)&Alo[id] = l;
}

// W [256,256] fp32 -> transposed hi/lo bf16 BT[n][k]; grid.y selects weight
__global__ __launch_bounds__(256) void wsplit_kernel(const float* __restrict__ W6,
                                                     const float* __restrict__ W7,
                                                     const float* __restrict__ Wp,
                                                     unsigned short* __restrict__ wt_hi,
                                                     unsigned short* __restrict__ wt_lo) {
    int id = blockIdx.x * 256 + threadIdx.x;  // 0..65535
    int wsel = blockIdx.y;
    const float* W = (wsel == 0) ? W6 : (wsel == 1) ? W7 : Wp;
    int n = id & 255, k = id >> 8;
    float v = W[k * 256 + n];
    unsigned short h = f2bf(v);
    wt_hi[(size_t)wsel * 65536 + n * 256 + k] = h;
    wt_lo[(size_t)wsel * 65536 + n * 256 + k] = f2bf(v - bf2f(h));
}

// ---------------------------------------------------------------------------
// MFMA GEMM (bf16x3), m97 structure: 128x128 tile, 4 waves, 64x64/wave, BK=32,
// global_load_lds(16B) into linear LDS [128][32], 2 barriers per K-step.
// A buffers are padded to N_PAD rows (no staging predication needed).
// MODE 0: bf16 output via LDS-bounce coalesced stores (output padded to N_PAD).
// MODE 1: f32 output + bias, direct predicated stores.
// ---------------------------------------------------------------------------

template <int MODE>
__global__ __launch_bounds__(256, 3) void gemm_mfma(
    const unsigned short* __restrict__ Ahi, const unsigned short* __restrict__ Alo,
    const unsigned short* __restrict__ BThi, const unsigned short* __restrict__ BTlo,
    const float* __restrict__ bias, void* __restrict__ Cout, int M, int nx) {
    // linear LDS: as_hi[0,4K) as_lo[4K,8K) bs_hi[8K,12K) bs_lo[12K,16K) ushorts
    __shared__ __align__(16) unsigned short lds[16384];  // 32 KB

    const int t = threadIdx.x;
    const int w = t >> 6, lane = t & 63;

    // bijective XCD swizzle (m204); pairs (x,y=0/1) adjacent within a chunk
    const int NWG = nx * 2;
    const int q = NWG >> 3, r = NWG & 7;
    const int orig = blockIdx.x;
    const int xcd = orig & 7, chunk_off = orig >> 3;
    const int wgid = (xcd < r) ? xcd * (q + 1) + chunk_off
                               : r * (q + 1) + (xcd - r) * q + chunk_off;
    const int m0 = (wgid >> 1) * 128;
    const int n0 = (wgid & 1) * 128;

    const int wr = (w >> 1) * 64, wc = (w & 1) * 64;
    const int lr = lane & 15;
    const int k8 = (lane >> 4) * 8;

    // staging: wave w stages rows [w*32, w*32+32) of each buffer; 2 issues x 16 rows
    const int srow = (w << 5) + (lane >> 2);
    const int scol = (lane & 3) << 3;
    const size_t ga0 = (size_t)(m0 + srow) * 256 + scol;
    const size_t ga1 = (size_t)(m0 + srow + 16) * 256 + scol;
    const size_t gb0 = (size_t)(n0 + srow) * 256 + scol;
    const size_t gb1 = (size_t)(n0 + srow + 16) * 256 + scol;
    unsigned short* l_ahi = &lds[0] + (w << 10);
    unsigned short* l_alo = &lds[4096] + (w << 10);
    unsigned short* l_bhi = &lds[8192] + (w << 10);
    unsigned short* l_blo = &lds[12288] + (w << 10);

    f32x4 acc[4][4];
#pragma unroll
    for (int i = 0; i < 4; ++i)
#pragma unroll
        for (int j = 0; j < 4; ++j) acc[i][j] = (f32x4){0.f, 0.f, 0.f, 0.f};

    for (int k0 = 0; k0 < 256; k0 += 32) {
        gl16(Ahi + ga0 + k0, l_ahi);
        gl16(Ahi + ga1 + k0, l_ahi + 512);
        gl16(Alo + ga0 + k0, l_alo);
        gl16(Alo + ga1 + k0, l_alo + 512);
        gl16(BThi + gb0 + k0, l_bhi);
        gl16(BThi + gb1 + k0, l_bhi + 512);
        gl16(BTlo + gb0 + k0, l_blo);
        gl16(BTlo + gb1 + k0, l_blo + 512);
        __syncthreads();   // compiler emits vmcnt(0) drain before barrier

        bf16x8 ah[4], al[4], bh[4], bl[4];
#pragma unroll
        for (int i = 0; i < 4; ++i) {
            ah[i] = *(const bf16x8*)&lds[(wr + i * 16 + lr) * 32 + k8];
            al[i] = *(const bf16x8*)&lds[4096 + (wr + i * 16 + lr) * 32 + k8];
            bh[i] = *(const bf16x8*)&lds[8192 + (wc + i * 16 + lr) * 32 + k8];
            bl[i] = *(const bf16x8*)&lds[12288 + (wc + i * 16 + lr) * 32 + k8];
        }
#pragma unroll
        for (int mi = 0; mi < 4; ++mi)
#pragma unroll
            for (int ni = 0; ni < 4; ++ni) {
                acc[mi][ni] = mfma_bf16(ah[mi], bh[ni], acc[mi][ni]);
                acc[mi][ni] = mfma_bf16(al[mi], bh[ni], acc[mi][ni]);
                acc[mi][ni] = mfma_bf16(ah[mi], bl[ni], acc[mi][ni]);
            }
        __syncthreads();
    }

    // D layout: row = 4*(lane>>4)+reg, col = lane&15  [m89-verified]
    if (MODE == 0) {
        // bounce through wave-private 8KB LDS tile [64][64] for coalesced stores
        unsigned short* eb = &lds[w * 4096];
        const int rq = 4 * (lane >> 4);
#pragma unroll
        for (int mi = 0; mi < 4; ++mi)
#pragma unroll
            for (int ni = 0; ni < 4; ++ni)
#pragma unroll
                for (int rr = 0; rr < 4; ++rr)
                    eb[(mi * 16 + rq + rr) * 64 + ni * 16 + lr] = f2bf(acc[mi][ni][rr]);
        // wave-private region: in-wave ds ordering handled by compiler waitcnts
        unsigned short* outp = (unsigned short*)Cout;
#pragma unroll
        for (int it = 0; it < 8; ++it) {
            int rl = it * 8 + (lane >> 3);
            bf16x8 vv = *(const bf16x8*)&eb[rl * 64 + (lane & 7) * 8];
            *(bf16x8*)&outp[(size_t)(m0 + wr + rl) * 256 + n0 + wc + (lane & 7) * 8] = vv;
        }
    } else {
        const int rbase = m0 + wr + 4 * (lane >> 4);
        float* outp = (float*)Cout;
#pragma unroll
        for (int ni = 0; ni < 4; ++ni) {
            const int col = n0 + wc + ni * 16 + lr;
            float bcol = bias[col];
#pragma unroll
            for (int mi = 0; mi < 4; ++mi) {
#pragma unroll
                for (int rr = 0; rr < 4; ++rr) {
                    int row = rbase + mi * 16 + rr;
                    if (row < M) outp[(size_t)row * 256 + col] = acc[mi][ni][rr] + bcol;
                }
            }
        }
    }
}

// ---------------------------------------------------------------------------
// Aggregation: 8 nodes/block, 32 lanes/node, 8 features/lane (bf16x8),
// 4 independent edge gathers in flight.
// ---------------------------------------------------------------------------

__global__ __launch_bounds__(256) void agg_split_kernel(const unsigned short* __restrict__ xt,
                                                        const int* __restrict__ row_ptr,
                                                        const int* __restrict__ csr_src,
                                                        const float* __restrict__ csr_w,
                                                        const float* __restrict__ bias,
                                                        unsigned short* __restrict__ Ahi,
                                                        unsigned short* __restrict__ Alo) {
    const int g = threadIdx.x >> 5;           // node slot 0..7
    const int l = threadIdx.x & 31;           // lane within node group
    const int v = blockIdx.x * 8 + g;
    const int d0 = l * 8;                     // this lane's 8 features

    const int s0 = row_ptr[v];
    const int s1 = row_ptr[v + 1];

    float acc[8] = {0.f, 0.f, 0.f, 0.f, 0.f, 0.f, 0.f, 0.f};

    int i = s0;
    for (; i + 4 <= s1; i += 4) {
        int   src[4];
        float wv[4];
#pragma unroll
        for (int u = 0; u < 4; ++u) { src[u] = csr_src[i + u]; wv[u] = csr_w[i + u]; }
        bf16x8 val[4];
#pragma unroll
        for (int u = 0; u < 4; ++u)
            val[u] = *(const bf16x8*)&xt[(size_t)src[u] * 256 + d0];
#pragma unroll
        for (int u = 0; u < 4; ++u)
#pragma unroll
            for (int j = 0; j < 8; ++j)
                acc[j] += bf2f((unsigned short)val[u][j]) * wv[u];
    }
    {
        int rem = s1 - i;
        int   src[3];
        float wv[3];
#pragma unroll
        for (int u = 0; u < 3; ++u) {
            src[u] = (u < rem) ? csr_src[i + u] : 0;
            wv[u]  = (u < rem) ? csr_w[i + u] : 0.f;
        }
        bf16x8 val[3];
#pragma unroll
        for (int u = 0; u < 3; ++u)
            val[u] = *(const bf16x8*)&xt[(size_t)src[u] * 256 + d0];
#pragma unroll
        for (int u = 0; u < 3; ++u)
#pragma unroll
            for (int j = 0; j < 8; ++j)
                acc[j] += bf2f((unsigned short)val[u][j]) * wv[u];
    }

    bf16x8 ho, lo;
#pragma unroll
    for (int j = 0; j < 8; ++j) {
        float r = acc[j] + bias[d0 + j];
        r = r > 0.f ? r : 0.f;
        unsigned short h = f2bf(r);
        ho[j] = (short)h;
        lo[j] = (short)f2bf(r - bf2f(h));
    }
    *(bf16x8*)&Ahi[(size_t)v * 256 + d0] = ho;
    *(bf16x8*)&Alo[(size_t)v * 256 + d0] = lo;
}

// ---------------------------------------------------------------------------

extern "C" void kernel_launch(void* const* d_in, const int* in_sizes, int n_in,
                              void* d_out, int out_size, void* d_ws, size_t ws_size,
                              hipStream_t stream) {
    (void)in_sizes; (void)n_in; (void)out_size; (void)ws_size;
    const float* h5 = (const float*)d_in[0];
    const int*   ei = (const int*)d_in[1];
    const float* ew = (const float*)d_in[2];
    const float* W6 = (const float*)d_in[3];
    const float* b6 = (const float*)d_in[4];
    const float* W7 = (const float*)d_in[5];
    const float* b7 = (const float*)d_in[6];
    const float* Wp = (const float*)d_in[7];
    const float* bp = (const float*)d_in[8];
    float* out = (float*)d_out;

    char* ws = (char*)d_ws;
    size_t off = 0;
    auto alloc = [&](size_t bytes) -> void* {
        void* p = ws + off;
        off = (off + bytes + 255) & ~(size_t)255;
        return p;
    };

    float* deg_out = (float*)alloc(N_NODES * 4);
    float* deg_in  = (float*)alloc(N_NODES * 4);
    int*   cnt     = (int*)alloc(N_NODES * 4);
    int*   row_ptr = (int*)alloc((N_NODES + 1) * 4);
    int*   partial = (int*)alloc(SCAN_NB * 4);
    float* nrm     = (float*)alloc(N_EDGES * 4);
    int*   csr_src = (int*)alloc(N_EDGES * 4);
    float* csr_w   = (float*)alloc(N_EDGES * 4);
    unsigned short* wt_hi = (unsigned short*)alloc(3 * 65536 * 2);
    unsigned short* wt_lo = (unsigned short*)alloc(3 * 65536 * 2);
    unsigned short* Ahi = (unsigned short*)alloc((size_t)N_PAD * 256 * 2);
    unsigned short* Alo = (unsigned short*)alloc((size_t)N_PAD * 256 * 2);
    unsigned short* xt  = (unsigned short*)alloc((size_t)N_PAD * 256 * 2);

    const int EB = (N_EDGES + 255) / 256;
    const int NX = (N_NODES + 127) / 128;   // 391
    const int NWG = NX * 2;                 // 782

    hipMemsetAsync(deg_out, 0, N_NODES * 4, stream);
    hipMemsetAsync(deg_in, 0, N_NODES * 4, stream);
    hipMemsetAsync(cnt, 0, N_NODES * 4, stream);

    deg_kernel<<<EB, 256, 0, stream>>>(ei, ew, deg_out, deg_in, cnt);
    norm_kernel<<<EB, 256, 0, stream>>>(ei, ew, deg_out, deg_in, nrm);
    scan1_kernel<<<SCAN_NB, 256, 0, stream>>>(cnt, partial);
    scan2_kernel<<<1, 256, 0, stream>>>(partial);
    scan3_kernel<<<SCAN_NB, 256, 0, stream>>>(cnt, partial, row_ptr);
    hipMemsetAsync(cnt, 0, N_NODES * 4, stream);
    fill_kernel<<<EB, 256, 0, stream>>>(ei, nrm, row_ptr, cnt, csr_src, csr_w);

    // input splits
    asplit_kernel<<<(N_NODES * 256 / 4 + 255) / 256, 256, 0, stream>>>(h5, Ahi, Alo);
    wsplit_kernel<<<dim3(256, 3), 256, 0, stream>>>(W6, W7, Wp, wt_hi, wt_lo);

    // layer 1
    gemm_mfma<0><<<NWG, 256, 0, stream>>>(Ahi, Alo, wt_hi, wt_lo, nullptr, xt, N_NODES, NX);
    agg_split_kernel<<<(N_NODES + 7) / 8, 256, 0, stream>>>(xt, row_ptr, csr_src, csr_w, b6, Ahi, Alo);

    // layer 2
    gemm_mfma<0><<<NWG, 256, 0, stream>>>(Ahi, Alo, wt_hi + 65536, wt_lo + 65536,
                                          nullptr, xt, N_NODES, NX);
    agg_split_kernel<<<(N_NODES + 7) / 8, 256, 0, stream>>>(xt, row_ptr, csr_src, csr_w, b7, Ahi, Alo);

    // head
    gemm_mfma<1><<<NWG, 256, 0, stream>>>(Ahi, Alo, wt_hi + 2 * 65536, wt_lo + 2 * 65536,
                                          bp, out, N_NODES, NX);
}

// Round 6
// 210.551 us; speedup vs baseline: 2.8363x; 1.2534x over previous
//
#include <hip/hip_runtime.h>

#define N_NODES 50000
#define N_PAD   50048            // 3128 * 16
#define N_PANELS 3128
#define N_EDGES 300000
#define DFEAT 256
#define EPS_F 1e-12f
#define SCAN_NB ((N_NODES + 255) / 256)   // 196

typedef _Float16 f16x8 __attribute__((ext_vector_type(8)));
typedef float f32x4 __attribute__((ext_vector_type(4)));

static __device__ inline f32x4 mfma_f16(f16x8 a, f16x8 b, f32x4 c) {
    return __builtin_amdgcn_mfma_f32_16x16x32_f16(a, b, c, 0, 0, 0);
}

// fragment-ready swizzled layout for a [R][256] f16 matrix:
// element (row, k) at ((row>>4)*8 + (k>>5))*512 + ((k>>3)&3)*128 + (row&15)*8 + (k&7)
// l = k-chunk index (k = l*8, l in 0..31)
static __device__ inline size_t swz(int row, int l) {
    return ((size_t)(row >> 4) * 8 + (l >> 2)) * 512 + (size_t)((l & 3) * 128 + (row & 15) * 8);
}

// ---------------------------------------------------------------------------
// Graph preprocessing
// ---------------------------------------------------------------------------

__global__ void deg_kernel(const int* __restrict__ ei, const float* __restrict__ ew,
                           float* __restrict__ deg_out, float* __restrict__ deg_in,
                           int* __restrict__ cnt) {
    int e = blockIdx.x * blockDim.x + threadIdx.x;
    if (e >= N_EDGES) return;
    int s = ei[e];
    int d = ei[N_EDGES + e];
    float w = ew[e];
    atomicAdd(&deg_out[s], w);
    atomicAdd(&deg_in[d], w);
    atomicAdd(&cnt[d], 1);
}

__global__ void norm_kernel(const int* __restrict__ ei, const float* __restrict__ ew,
                            const float* __restrict__ deg_out, const float* __restrict__ deg_in,
                            float* __restrict__ nrm) {
    int e = blockIdx.x * blockDim.x + threadIdx.x;
    if (e >= N_EDGES) return;
    int s = ei[e];
    int d = ei[N_EDGES + e];
    nrm[e] = ew[e] * rsqrtf(deg_out[s] * deg_in[d] + EPS_F);
}

// --- 3-kernel decomposed exclusive scan of cnt -> row_ptr -------------------

__global__ __launch_bounds__(256) void scan1_kernel(const int* __restrict__ cnt,
                                                    int* __restrict__ partial) {
    __shared__ int sh[256];
    int i = blockIdx.x * 256 + threadIdx.x;
    int v = (i < N_NODES) ? cnt[i] : 0;
    sh[threadIdx.x] = v;
    __syncthreads();
    for (int off = 128; off > 0; off >>= 1) {
        if (threadIdx.x < (unsigned)off) sh[threadIdx.x] += sh[threadIdx.x + off];
        __syncthreads();
    }
    if (threadIdx.x == 0) partial[blockIdx.x] = sh[0];
}

__global__ __launch_bounds__(256) void scan2_kernel(int* __restrict__ partial) {
    __shared__ int sh[256];
    int t = threadIdx.x;
    int v = (t < SCAN_NB) ? partial[t] : 0;
    sh[t] = v;
    __syncthreads();
    for (int off = 1; off < 256; off <<= 1) {
        int x = (t >= off) ? sh[t - off] : 0;
        __syncthreads();
        sh[t] += x;
        __syncthreads();
    }
    if (t < SCAN_NB) partial[t] = sh[t] - v;  // exclusive
}

__global__ __launch_bounds__(256) void scan3_kernel(const int* __restrict__ cnt,
                                                    const int* __restrict__ partial,
                                                    int* __restrict__ row_ptr) {
    __shared__ int sh[256];
    int t = threadIdx.x;
    int i = blockIdx.x * 256 + t;
    int v = (i < N_NODES) ? cnt[i] : 0;
    sh[t] = v;
    __syncthreads();
    for (int off = 1; off < 256; off <<= 1) {
        int x = (t >= off) ? sh[t - off] : 0;
        __syncthreads();
        sh[t] += x;
        __syncthreads();
    }
    if (i < N_NODES) row_ptr[i] = sh[t] - v + partial[blockIdx.x];
    if (i == 0) row_ptr[N_NODES] = N_EDGES;
}

__global__ void fill_kernel(const int* __restrict__ ei, const float* __restrict__ nrm,
                            const int* __restrict__ row_ptr, int* __restrict__ cur,
                            int* __restrict__ csr_src, float* __restrict__ csr_w) {
    int e = blockIdx.x * blockDim.x + threadIdx.x;
    if (e >= N_EDGES) return;
    int d = ei[N_EDGES + e];
    int pos = atomicAdd(&cur[d], 1);
    int slot = row_ptr[d] + pos;
    csr_src[slot] = ei[e];
    csr_w[slot] = nrm[e];
}

// ---------------------------------------------------------------------------
// fp16 conversions of inputs (into fragment-swizzled layouts)
// ---------------------------------------------------------------------------

// h5 [N,256] f32 -> A_sw f16 swizzled; pad rows -> 0
__global__ __launch_bounds__(256) void asplit_kernel(const float* __restrict__ X,
                                                     _Float16* __restrict__ Asw) {
    int tid = blockIdx.x * 256 + threadIdx.x;   // 0 .. N_PAD*32
    int row = tid >> 5, l = tid & 31;
    f16x8 o;
    if (row < N_NODES) {
        const float* p = &X[(size_t)row * 256 + l * 8];
        float4 v0 = *(const float4*)p;
        float4 v1 = *(const float4*)(p + 4);
        o[0] = (_Float16)v0.x; o[1] = (_Float16)v0.y;
        o[2] = (_Float16)v0.z; o[3] = (_Float16)v0.w;
        o[4] = (_Float16)v1.x; o[5] = (_Float16)v1.y;
        o[6] = (_Float16)v1.z; o[7] = (_Float16)v1.w;
    } else {
        o = (f16x8)(_Float16)0.f;
    }
    *(f16x8*)&Asw[swz(row, l)] = o;
}

// W [256k,256n] f32 -> B_sw f16: fragment layout over (col=n, k); 3 weights
__global__ __launch_bounds__(256) void wsplit_kernel(const float* __restrict__ W6,
                                                     const float* __restrict__ W7,
                                                     const float* __restrict__ Wp,
                                                     _Float16* __restrict__ Bsw) {
    int id = blockIdx.x * 256 + threadIdx.x;    // 0..8191 per weight
    int wsel = blockIdx.y;
    const float* W = (wsel == 0) ? W6 : (wsel == 1) ? W7 : Wp;
    int n = id >> 5, l = id & 31;
    f16x8 o;
#pragma unroll
    for (int j = 0; j < 8; ++j)
        o[j] = (_Float16)W[(l * 8 + j) * 256 + n];
    *(f16x8*)&Bsw[(size_t)wsel * 65536 + swz(n, l)] = o;
}

// ---------------------------------------------------------------------------
// fp16 register-resident-B GEMM: C[M,256] = A[M,256] @ W[256,256]
// grid-stride over 16-row panels; 4 waves/block each owning 64 cols;
// B-frags held in VGPRs for the whole kernel; no barriers, no staging LDS.
// MODE 0: f16 row-major output (gather buffer). MODE 1: f32 + bias (head).
// ---------------------------------------------------------------------------

template <int MODE>
__global__ __launch_bounds__(256) void gemm_f16(const _Float16* __restrict__ Asw,
                                                const _Float16* __restrict__ Bsw,
                                                const float* __restrict__ bias,
                                                void* __restrict__ Cout, int M) {
    __shared__ _Float16 ebuf[4][16 * 72];   // MODE0 epilogue bounce, row-padded

    const int t = threadIdx.x;
    const int w = t >> 6, lane = t & 63;
    const int lr = lane & 15;

    // prologue: wave's 64-col B slice as 32 fragments (held in VGPRs)
    f16x8 bf[4][8];
#pragma unroll
    for (int cp4 = 0; cp4 < 4; ++cp4)
#pragma unroll
        for (int kb = 0; kb < 8; ++kb)
            bf[cp4][kb] = *(const f16x8*)&Bsw[(size_t)((w * 4 + cp4) * 8 + kb) * 512 + lane * 8];

    float bc[4];
    if (MODE == 1) {
#pragma unroll
        for (int cp4 = 0; cp4 < 4; ++cp4) bc[cp4] = bias[w * 64 + cp4 * 16 + lr];
    }

    for (int p = blockIdx.x; p < N_PANELS; p += gridDim.x) {
        const _Float16* abase = &Asw[(size_t)p * 4096 + lane * 8];
        f16x8 af[8];
#pragma unroll
        for (int kb = 0; kb < 8; ++kb)
            af[kb] = *(const f16x8*)&abase[kb * 512];

        f32x4 acc[4];
#pragma unroll
        for (int cp4 = 0; cp4 < 4; ++cp4) acc[cp4] = (f32x4){0.f, 0.f, 0.f, 0.f};

#pragma unroll
        for (int kb = 0; kb < 8; ++kb)
#pragma unroll
            for (int cp4 = 0; cp4 < 4; ++cp4)
                acc[cp4] = mfma_f16(af[kb], bf[cp4][kb], acc[cp4]);

        // D layout: row = 4*(lane>>4)+reg, col = lane&15  [m89-verified]
        if (MODE == 0) {
            _Float16* eb = ebuf[w];
            const int rq = 4 * (lane >> 4);
#pragma unroll
            for (int cp4 = 0; cp4 < 4; ++cp4)
#pragma unroll
                for (int rr = 0; rr < 4; ++rr)
                    eb[(rq + rr) * 72 + cp4 * 16 + lr] = (_Float16)acc[cp4][rr];
            // wave-private region; in-wave DS ordering via compiler lgkm waits
            _Float16* xp = (_Float16*)Cout;
#pragma unroll
            for (int it = 0; it < 2; ++it) {
                int rl = it * 8 + (lane >> 3);
                f16x8 v = *(const f16x8*)&eb[rl * 72 + (lane & 7) * 8];
                *(f16x8*)&xp[(size_t)(p * 16 + rl) * 256 + w * 64 + (lane & 7) * 8] = v;
            }
        } else {
            float* op = (float*)Cout;
            const int rbase = p * 16 + 4 * (lane >> 4);
#pragma unroll
            for (int cp4 = 0; cp4 < 4; ++cp4) {
                const int col = w * 64 + cp4 * 16 + lr;
#pragma unroll
                for (int rr = 0; rr < 4; ++rr) {
                    int row = rbase + rr;
                    if (row < M) op[(size_t)row * 256 + col] = acc[cp4][rr] + bc[cp4];
                }
            }
        }
    }
}

// ---------------------------------------------------------------------------
// Aggregation: 8 nodes/block, 32 lanes/node, 8 features/lane (f16x8),
// 4 independent edge gathers in flight; writes fragment-swizzled f16 output.
// ---------------------------------------------------------------------------

__global__ __launch_bounds__(256) void agg_kernel(const _Float16* __restrict__ xt,
                                                  const int* __restrict__ row_ptr,
                                                  const int* __restrict__ csr_src,
                                                  const float* __restrict__ csr_w,
                                                  const float* __restrict__ bias,
                                                  _Float16* __restrict__ Asw) {
    const int g = threadIdx.x >> 5;
    const int l = threadIdx.x & 31;
    const int v = blockIdx.x * 8 + g;
    const int d0 = l * 8;

    const int s0 = row_ptr[v];
    const int s1 = row_ptr[v + 1];

    float acc[8] = {0.f, 0.f, 0.f, 0.f, 0.f, 0.f, 0.f, 0.f};

    int i = s0;
    for (; i + 4 <= s1; i += 4) {
        int   src[4];
        float wv[4];
#pragma unroll
        for (int u = 0; u < 4; ++u) { src[u] = csr_src[i + u]; wv[u] = csr_w[i + u]; }
        f16x8 val[4];
#pragma unroll
        for (int u = 0; u < 4; ++u)
            val[u] = *(const f16x8*)&xt[(size_t)src[u] * 256 + d0];
#pragma unroll
        for (int u = 0; u < 4; ++u)
#pragma unroll
            for (int j = 0; j < 8; ++j)
                acc[j] += (float)val[u][j] * wv[u];
    }
    {
        int rem = s1 - i;
        int   src[3];
        float wv[3];
#pragma unroll
        for (int u = 0; u < 3; ++u) {
            src[u] = (u < rem) ? csr_src[i + u] : 0;
            wv[u]  = (u < rem) ? csr_w[i + u] : 0.f;
        }
        f16x8 val[3];
#pragma unroll
        for (int u = 0; u < 3; ++u)
            val[u] = *(const f16x8*)&xt[(size_t)src[u] * 256 + d0];
#pragma unroll
        for (int u = 0; u < 3; ++u)
#pragma unroll
            for (int j = 0; j < 8; ++j)
                acc[j] += (float)val[u][j] * wv[u];
    }

    f16x8 o;
#pragma unroll
    for (int j = 0; j < 8; ++j) {
        float r = acc[j] + bias[d0 + j];
        r = r > 0.f ? r : 0.f;
        o[j] = (_Float16)r;
    }
    *(f16x8*)&Asw[swz(v, l)] = o;
}

// ---------------------------------------------------------------------------

extern "C" void kernel_launch(void* const* d_in, const int* in_sizes, int n_in,
                              void* d_out, int out_size, void* d_ws, size_t ws_size,
                              hipStream_t stream) {
    (void)in_sizes; (void)n_in; (void)out_size; (void)ws_size;
    const float* h5 = (const float*)d_in[0];
    const int*   ei = (const int*)d_in[1];
    const float* ew = (const float*)d_in[2];
    const float* W6 = (const float*)d_in[3];
    const float* b6 = (const float*)d_in[4];
    const float* W7 = (const float*)d_in[5];
    const float* b7 = (const float*)d_in[6];
    const float* Wp = (const float*)d_in[7];
    const float* bp = (const float*)d_in[8];
    float* out = (float*)d_out;

    char* ws = (char*)d_ws;
    size_t off = 0;
    auto alloc = [&](size_t bytes) -> void* {
        void* p = ws + off;
        off = (off + bytes + 255) & ~(size_t)255;
        return p;
    };

    float* deg_out = (float*)alloc(N_NODES * 4);
    float* deg_in  = (float*)alloc(N_NODES * 4);
    int*   cnt     = (int*)alloc(N_NODES * 4);
    int*   row_ptr = (int*)alloc((N_NODES + 1) * 4);
    int*   partial = (int*)alloc(SCAN_NB * 4);
    float* nrm     = (float*)alloc(N_EDGES * 4);
    int*   csr_src = (int*)alloc(N_EDGES * 4);
    float* csr_w   = (float*)alloc(N_EDGES * 4);
    _Float16* Bsw  = (_Float16*)alloc(3 * 65536 * 2);
    _Float16* Asw  = (_Float16*)alloc((size_t)N_PAD * 256 * 2);
    _Float16* xt   = (_Float16*)alloc((size_t)N_PAD * 256 * 2);

    const int EB = (N_EDGES + 255) / 256;
    const int GB = 512;   // gemm grid (grid-stride over 3128 panels)

    hipMemsetAsync(deg_out, 0, N_NODES * 4, stream);
    hipMemsetAsync(deg_in, 0, N_NODES * 4, stream);
    hipMemsetAsync(cnt, 0, N_NODES * 4, stream);

    deg_kernel<<<EB, 256, 0, stream>>>(ei, ew, deg_out, deg_in, cnt);
    norm_kernel<<<EB, 256, 0, stream>>>(ei, ew, deg_out, deg_in, nrm);
    scan1_kernel<<<SCAN_NB, 256, 0, stream>>>(cnt, partial);
    scan2_kernel<<<1, 256, 0, stream>>>(partial);
    scan3_kernel<<<SCAN_NB, 256, 0, stream>>>(cnt, partial, row_ptr);
    hipMemsetAsync(cnt, 0, N_NODES * 4, stream);
    fill_kernel<<<EB, 256, 0, stream>>>(ei, nrm, row_ptr, cnt, csr_src, csr_w);

    // input conversions
    asplit_kernel<<<N_PAD * 32 / 256, 256, 0, stream>>>(h5, Asw);
    wsplit_kernel<<<dim3(32, 3), 256, 0, stream>>>(W6, W7, Wp, Bsw);

    // layer 1
    gemm_f16<0><<<GB, 256, 0, stream>>>(Asw, Bsw, nullptr, xt, N_PAD);
    agg_kernel<<<N_NODES / 8, 256, 0, stream>>>(xt, row_ptr, csr_src, csr_w, b6, Asw);

    // layer 2
    gemm_f16<0><<<GB, 256, 0, stream>>>(Asw, Bsw + 65536, nullptr, xt, N_PAD);
    agg_kernel<<<N_NODES / 8, 256, 0, stream>>>(xt, row_ptr, csr_src, csr_w, b7, Asw);

    // head
    gemm_f16<1><<<GB, 256, 0, stream>>>(Asw, Bsw + 2 * 65536, bp, out, N_NODES);
}

// Round 7
// 182.830 us; speedup vs baseline: 3.2664x; 1.1516x over previous
//
#include <hip/hip_runtime.h>

#define N_NODES 50000
#define N_PAD   50048            // 3128 * 16
#define N_PANELS 3128
#define N_EDGES 300000
#define DFEAT 256
#define EPS_F 1e-12f
#define SCAN_NB ((N_NODES + 255) / 256)   // 196
#define MASK48 ((1ull << 48) - 1)

typedef _Float16 f16x8 __attribute__((ext_vector_type(8)));
typedef float f32x4 __attribute__((ext_vector_type(4)));

static __device__ inline f32x4 mfma_f16(f16x8 a, f16x8 b, f32x4 c) {
    return __builtin_amdgcn_mfma_f32_16x16x32_f16(a, b, c, 0, 0, 0);
}

// fragment-ready swizzled layout for a [R][256] f16 matrix:
// element (row, k) at ((row>>4)*8 + (k>>5))*512 + ((k>>3)&3)*128 + (row&15)*8 + (k&7)
static __device__ inline size_t swz(int row, int l) {
    return ((size_t)(row >> 4) * 8 + (l >> 2)) * 512 + (size_t)((l & 3) * 128 + (row & 15) * 8);
}

// ---------------------------------------------------------------------------
// Graph preprocessing
// ---------------------------------------------------------------------------

// 2 packed fixed-point atomics per edge:
//   pk_in[d]  += (1<<48) | (w * 2^32)    (cnt in high 16, sum in low 48)
//   pk_out[s] += (w * 2^32)
__global__ void deg_kernel(const int* __restrict__ ei, const float* __restrict__ ew,
                           unsigned long long* __restrict__ pk_out,
                           unsigned long long* __restrict__ pk_in) {
    int e = blockIdx.x * blockDim.x + threadIdx.x;
    if (e >= N_EDGES) return;
    int s = ei[e];
    int d = ei[N_EDGES + e];
    unsigned long long wfx = (unsigned long long)(ew[e] * 4294967296.0f);
    atomicAdd(&pk_out[s], wfx);
    atomicAdd(&pk_in[d], (1ull << 48) | wfx);
}

// --- decomposed exclusive scan of cnt(packed) -> row_ptr; unpack degs -------

__global__ __launch_bounds__(256) void scan1_kernel(const unsigned long long* __restrict__ pk_in,
                                                    const unsigned long long* __restrict__ pk_out,
                                                    float* __restrict__ deg_in,
                                                    float* __restrict__ deg_out,
                                                    int* __restrict__ partial) {
    __shared__ int sh[256];
    int i = blockIdx.x * 256 + threadIdx.x;
    int c = 0;
    if (i < N_NODES) {
        unsigned long long p = pk_in[i];
        c = (int)(p >> 48);
        deg_in[i] = (float)(p & MASK48) * 0x1p-32f;
        deg_out[i] = (float)pk_out[i] * 0x1p-32f;
    }
    sh[threadIdx.x] = c;
    __syncthreads();
    for (int off = 128; off > 0; off >>= 1) {
        if (threadIdx.x < (unsigned)off) sh[threadIdx.x] += sh[threadIdx.x + off];
        __syncthreads();
    }
    if (threadIdx.x == 0) partial[blockIdx.x] = sh[0];
}

__global__ __launch_bounds__(256) void scan2_kernel(int* __restrict__ partial) {
    __shared__ int sh[256];
    int t = threadIdx.x;
    int v = (t < SCAN_NB) ? partial[t] : 0;
    sh[t] = v;
    __syncthreads();
    for (int off = 1; off < 256; off <<= 1) {
        int x = (t >= off) ? sh[t - off] : 0;
        __syncthreads();
        sh[t] += x;
        __syncthreads();
    }
    if (t < SCAN_NB) partial[t] = sh[t] - v;  // exclusive
}

__global__ __launch_bounds__(256) void scan3_kernel(const unsigned long long* __restrict__ pk_in,
                                                    const int* __restrict__ partial,
                                                    int* __restrict__ row_ptr) {
    __shared__ int sh[256];
    int t = threadIdx.x;
    int i = blockIdx.x * 256 + t;
    int v = (i < N_NODES) ? (int)(pk_in[i] >> 48) : 0;
    sh[t] = v;
    __syncthreads();
    for (int off = 1; off < 256; off <<= 1) {
        int x = (t >= off) ? sh[t - off] : 0;
        __syncthreads();
        sh[t] += x;
        __syncthreads();
    }
    if (i < N_NODES) row_ptr[i] = sh[t] - v + partial[blockIdx.x];
    if (i == 0) row_ptr[N_NODES] = N_EDGES;
}

// fused fill + norm: one packed {src, norm} store per CSR slot
__global__ void fill_kernel(const int* __restrict__ ei, const float* __restrict__ ew,
                            const float* __restrict__ deg_out, const float* __restrict__ deg_in,
                            const int* __restrict__ row_ptr, int* __restrict__ cur,
                            int2* __restrict__ csr) {
    int e = blockIdx.x * blockDim.x + threadIdx.x;
    if (e >= N_EDGES) return;
    int s = ei[e];
    int d = ei[N_EDGES + e];
    float nm = ew[e] * rsqrtf(deg_out[s] * deg_in[d] + EPS_F);
    int pos = atomicAdd(&cur[d], 1);
    csr[row_ptr[d] + pos] = make_int2(s, __float_as_int(nm));
}

// ---------------------------------------------------------------------------
// fp16 conversions of inputs (into fragment-swizzled layouts)
// ---------------------------------------------------------------------------

__global__ __launch_bounds__(256) void asplit_kernel(const float* __restrict__ X,
                                                     _Float16* __restrict__ Asw) {
    int tid = blockIdx.x * 256 + threadIdx.x;   // 0 .. N_PAD*32
    int row = tid >> 5, l = tid & 31;
    f16x8 o;
    if (row < N_NODES) {
        const float* p = &X[(size_t)row * 256 + l * 8];
        float4 v0 = *(const float4*)p;
        float4 v1 = *(const float4*)(p + 4);
        o[0] = (_Float16)v0.x; o[1] = (_Float16)v0.y;
        o[2] = (_Float16)v0.z; o[3] = (_Float16)v0.w;
        o[4] = (_Float16)v1.x; o[5] = (_Float16)v1.y;
        o[6] = (_Float16)v1.z; o[7] = (_Float16)v1.w;
    } else {
        o = (f16x8)(_Float16)0.f;
    }
    *(f16x8*)&Asw[swz(row, l)] = o;
}

// W [256k,256n] f32 -> B_sw f16: fragment layout over (col=n, k); 3 weights
__global__ __launch_bounds__(256) void wsplit_kernel(const float* __restrict__ W6,
                                                     const float* __restrict__ W7,
                                                     const float* __restrict__ Wp,
                                                     _Float16* __restrict__ Bsw) {
    int id = blockIdx.x * 256 + threadIdx.x;    // 0..8191 per weight
    int wsel = blockIdx.y;
    const float* W = (wsel == 0) ? W6 : (wsel == 1) ? W7 : Wp;
    int n = id >> 5, l = id & 31;
    f16x8 o;
#pragma unroll
    for (int j = 0; j < 8; ++j)
        o[j] = (_Float16)W[(l * 8 + j) * 256 + n];
    *(f16x8*)&Bsw[(size_t)wsel * 65536 + swz(n, l)] = o;
}

// ---------------------------------------------------------------------------
// fp16 register-resident-B GEMM: C[M,256] = A[M,256] @ W[256,256]
// grid-stride over 16-row panels; 4 waves/block each owning 64 cols;
// B-frags held in VGPRs; no barriers, no staging LDS.
// MODE 0: f16 row-major output. MODE 1: f32 + bias (head).
// ---------------------------------------------------------------------------

template <int MODE>
__global__ __launch_bounds__(256) void gemm_f16(const _Float16* __restrict__ Asw,
                                                const _Float16* __restrict__ Bsw,
                                                const float* __restrict__ bias,
                                                void* __restrict__ Cout, int M) {
    __shared__ _Float16 ebuf[4][16 * 72];   // MODE0 epilogue bounce, row-padded

    const int t = threadIdx.x;
    const int w = t >> 6, lane = t & 63;
    const int lr = lane & 15;

    f16x8 bf[4][8];
#pragma unroll
    for (int cp4 = 0; cp4 < 4; ++cp4)
#pragma unroll
        for (int kb = 0; kb < 8; ++kb)
            bf[cp4][kb] = *(const f16x8*)&Bsw[(size_t)((w * 4 + cp4) * 8 + kb) * 512 + lane * 8];

    float bc[4];
    if (MODE == 1) {
#pragma unroll
        for (int cp4 = 0; cp4 < 4; ++cp4) bc[cp4] = bias[w * 64 + cp4 * 16 + lr];
    }

    for (int p = blockIdx.x; p < N_PANELS; p += gridDim.x) {
        const _Float16* abase = &Asw[(size_t)p * 4096 + lane * 8];
        f16x8 af[8];
#pragma unroll
        for (int kb = 0; kb < 8; ++kb)
            af[kb] = *(const f16x8*)&abase[kb * 512];

        f32x4 acc[4];
#pragma unroll
        for (int cp4 = 0; cp4 < 4; ++cp4) acc[cp4] = (f32x4){0.f, 0.f, 0.f, 0.f};

#pragma unroll
        for (int kb = 0; kb < 8; ++kb)
#pragma unroll
            for (int cp4 = 0; cp4 < 4; ++cp4)
                acc[cp4] = mfma_f16(af[kb], bf[cp4][kb], acc[cp4]);

        // D layout: row = 4*(lane>>4)+reg, col = lane&15  [m89-verified]
        if (MODE == 0) {
            _Float16* eb = ebuf[w];
            const int rq = 4 * (lane >> 4);
#pragma unroll
            for (int cp4 = 0; cp4 < 4; ++cp4)
#pragma unroll
                for (int rr = 0; rr < 4; ++rr)
                    eb[(rq + rr) * 72 + cp4 * 16 + lr] = (_Float16)acc[cp4][rr];
            _Float16* xp = (_Float16*)Cout;
#pragma unroll
            for (int it = 0; it < 2; ++it) {
                int rl = it * 8 + (lane >> 3);
                f16x8 v = *(const f16x8*)&eb[rl * 72 + (lane & 7) * 8];
                *(f16x8*)&xp[(size_t)(p * 16 + rl) * 256 + w * 64 + (lane & 7) * 8] = v;
            }
        } else {
            float* op = (float*)Cout;
            const int rbase = p * 16 + 4 * (lane >> 4);
#pragma unroll
            for (int cp4 = 0; cp4 < 4; ++cp4) {
                const int col = w * 64 + cp4 * 16 + lr;
#pragma unroll
                for (int rr = 0; rr < 4; ++rr) {
                    int row = rbase + rr;
                    if (row < M) op[(size_t)row * 256 + col] = acc[cp4][rr] + bc[cp4];
                }
            }
        }
    }
}

// ---------------------------------------------------------------------------
// Aggregation: 8 nodes/block, 32 lanes/node, 8 features/lane (f16x8),
// 4 independent edge gathers in flight; packed {src,norm} CSR headers.
// ---------------------------------------------------------------------------

__global__ __launch_bounds__(256) void agg_kernel(const _Float16* __restrict__ xt,
                                                  const int* __restrict__ row_ptr,
                                                  const int2* __restrict__ csr,
                                                  const float* __restrict__ bias,
                                                  _Float16* __restrict__ Asw) {
    const int g = threadIdx.x >> 5;
    const int l = threadIdx.x & 31;
    const int v = blockIdx.x * 8 + g;
    const int d0 = l * 8;

    const int s0 = row_ptr[v];
    const int s1 = row_ptr[v + 1];

    float acc[8] = {0.f, 0.f, 0.f, 0.f, 0.f, 0.f, 0.f, 0.f};

    int i = s0;
    for (; i + 4 <= s1; i += 4) {
        int2 hd[4];
#pragma unroll
        for (int u = 0; u < 4; ++u) hd[u] = csr[i + u];
        f16x8 val[4];
#pragma unroll
        for (int u = 0; u < 4; ++u)
            val[u] = *(const f16x8*)&xt[(size_t)hd[u].x * 256 + d0];
#pragma unroll
        for (int u = 0; u < 4; ++u) {
            float wv = __int_as_float(hd[u].y);
#pragma unroll
            for (int j = 0; j < 8; ++j)
                acc[j] += (float)val[u][j] * wv;
        }
    }
    {
        int rem = s1 - i;
        int2 hd[3];
#pragma unroll
        for (int u = 0; u < 3; ++u)
            hd[u] = (u < rem) ? csr[i + u] : make_int2(0, 0);
        f16x8 val[3];
#pragma unroll
        for (int u = 0; u < 3; ++u)
            val[u] = *(const f16x8*)&xt[(size_t)hd[u].x * 256 + d0];
#pragma unroll
        for (int u = 0; u < 3; ++u) {
            float wv = __int_as_float(hd[u].y);
#pragma unroll
            for (int j = 0; j < 8; ++j)
                acc[j] += (float)val[u][j] * wv;
        }
    }

    f16x8 o;
#pragma unroll
    for (int j = 0; j < 8; ++j) {
        float r = acc[j] + bias[d0 + j];
        r = r > 0.f ? r : 0.f;
        o[j] = (_Float16)r;
    }
    *(f16x8*)&Asw[swz(v, l)] = o;
}

// ---------------------------------------------------------------------------

extern "C" void kernel_launch(void* const* d_in, const int* in_sizes, int n_in,
                              void* d_out, int out_size, void* d_ws, size_t ws_size,
                              hipStream_t stream) {
    (void)in_sizes; (void)n_in; (void)out_size; (void)ws_size;
    const float* h5 = (const float*)d_in[0];
    const int*   ei = (const int*)d_in[1];
    const float* ew = (const float*)d_in[2];
    const float* W6 = (const float*)d_in[3];
    const float* b6 = (const float*)d_in[4];
    const float* W7 = (const float*)d_in[5];
    const float* b7 = (const float*)d_in[6];
    const float* Wp = (const float*)d_in[7];
    const float* bp = (const float*)d_in[8];
    float* out = (float*)d_out;

    char* ws = (char*)d_ws;
    size_t off = 0;
    auto alloc = [&](size_t bytes) -> void* {
        void* p = ws + off;
        off = (off + bytes + 255) & ~(size_t)255;
        return p;
    };

    // single zeroed region: pk_out (400K) | pk_in (400K) | cur (200K)
    char* zblk = (char*)alloc(N_NODES * 8 * 2 + N_NODES * 4);
    unsigned long long* pk_out = (unsigned long long*)zblk;
    unsigned long long* pk_in  = (unsigned long long*)(zblk + N_NODES * 8);
    int* cur = (int*)(zblk + N_NODES * 16);

    float* deg_out = (float*)alloc(N_NODES * 4);
    float* deg_in  = (float*)alloc(N_NODES * 4);
    int*   row_ptr = (int*)alloc((N_NODES + 1) * 4);
    int*   partial = (int*)alloc(SCAN_NB * 4);
    int2*  csr     = (int2*)alloc(N_EDGES * 8);
    _Float16* Bsw  = (_Float16*)alloc(3 * 65536 * 2);
    _Float16* Asw  = (_Float16*)alloc((size_t)N_PAD * 256 * 2);
    _Float16* xt   = (_Float16*)alloc((size_t)N_PAD * 256 * 2);

    const int EB = (N_EDGES + 255) / 256;
    const int GB = 512;   // gemm grid (grid-stride over 3128 panels)

    hipMemsetAsync(zblk, 0, N_NODES * 8 * 2 + N_NODES * 4, stream);

    deg_kernel<<<EB, 256, 0, stream>>>(ei, ew, pk_out, pk_in);
    scan1_kernel<<<SCAN_NB, 256, 0, stream>>>(pk_in, pk_out, deg_in, deg_out, partial);
    scan2_kernel<<<1, 256, 0, stream>>>(partial);
    scan3_kernel<<<SCAN_NB, 256, 0, stream>>>(pk_in, partial, row_ptr);
    fill_kernel<<<EB, 256, 0, stream>>>(ei, ew, deg_out, deg_in, row_ptr, cur, csr);

    // input conversions
    asplit_kernel<<<N_PAD * 32 / 256, 256, 0, stream>>>(h5, Asw);
    wsplit_kernel<<<dim3(32, 3), 256, 0, stream>>>(W6, W7, Wp, Bsw);

    // layer 1
    gemm_f16<0><<<GB, 256, 0, stream>>>(Asw, Bsw, nullptr, xt, N_PAD);
    agg_kernel<<<N_NODES / 8, 256, 0, stream>>>(xt, row_ptr, csr, b6, Asw);

    // layer 2
    gemm_f16<0><<<GB, 256, 0, stream>>>(Asw, Bsw + 65536, nullptr, xt, N_PAD);
    agg_kernel<<<N_NODES / 8, 256, 0, stream>>>(xt, row_ptr, csr, b7, Asw);

    // head
    gemm_f16<1><<<GB, 256, 0, stream>>>(Asw, Bsw + 2 * 65536, bp, out, N_NODES);
}

// Round 8
// 182.658 us; speedup vs baseline: 3.2695x; 1.0009x over previous
//
#include <hip/hip_runtime.h>

#define N_NODES 50000
#define N_PAD   50048            // 3128 * 16
#define N_PANELS 3128
#define N_EDGES 300000
#define DFEAT 256
#define EPS_F 1e-12f
#define SCAN_NB ((N_NODES + 255) / 256)   // 196
#define MASK48 ((1ull << 48) - 1)
#define ZBYTES (N_NODES * 20)             // pk_out(8) + pk_in(8) + cur(4) per node

typedef _Float16 f16x8 __attribute__((ext_vector_type(8)));
typedef float f32x4 __attribute__((ext_vector_type(4)));

static __device__ inline f32x4 mfma_f16(f16x8 a, f16x8 b, f32x4 c) {
    return __builtin_amdgcn_mfma_f32_16x16x32_f16(a, b, c, 0, 0, 0);
}

// fragment-ready swizzled layout for a [R][256] f16 matrix:
// element (row, k) at ((row>>4)*8 + (k>>5))*512 + ((k>>3)&3)*128 + (row&15)*8 + (k&7)
static __device__ inline size_t swz(int row, int l) {
    return ((size_t)(row >> 4) * 8 + (l >> 2)) * 512 + (size_t)((l & 3) * 128 + (row & 15) * 8);
}

// ---------------------------------------------------------------------------
// Workspace zero-init (replaces pathologically slow runtime fillBuffer)
// ---------------------------------------------------------------------------

__global__ __launch_bounds__(256) void zero_kernel(int4* __restrict__ p, int n16) {
    int i = blockIdx.x * 256 + threadIdx.x;
    if (i < n16) p[i] = make_int4(0, 0, 0, 0);
}

// ---------------------------------------------------------------------------
// Graph preprocessing
// ---------------------------------------------------------------------------

// 2 packed fixed-point atomics per edge:
//   pk_in[d]  += (1<<48) | (w * 2^32)    (cnt in high 16, sum in low 48)
//   pk_out[s] += (w * 2^32)
__global__ void deg_kernel(const int* __restrict__ ei, const float* __restrict__ ew,
                           unsigned long long* __restrict__ pk_out,
                           unsigned long long* __restrict__ pk_in) {
    int e = blockIdx.x * blockDim.x + threadIdx.x;
    if (e >= N_EDGES) return;
    int s = ei[e];
    int d = ei[N_EDGES + e];
    unsigned long long wfx = (unsigned long long)(ew[e] * 4294967296.0f);
    atomicAdd(&pk_out[s], wfx);
    atomicAdd(&pk_in[d], (1ull << 48) | wfx);
}

// --- decomposed exclusive scan of cnt(packed) -> row_ptr; unpack degs -------

__global__ __launch_bounds__(256) void scan1_kernel(const unsigned long long* __restrict__ pk_in,
                                                    const unsigned long long* __restrict__ pk_out,
                                                    float* __restrict__ deg_in,
                                                    float* __restrict__ deg_out,
                                                    int* __restrict__ partial) {
    __shared__ int sh[256];
    int i = blockIdx.x * 256 + threadIdx.x;
    int c = 0;
    if (i < N_NODES) {
        unsigned long long p = pk_in[i];
        c = (int)(p >> 48);
        deg_in[i] = (float)(p & MASK48) * 0x1p-32f;
        deg_out[i] = (float)pk_out[i] * 0x1p-32f;
    }
    sh[threadIdx.x] = c;
    __syncthreads();
    for (int off = 128; off > 0; off >>= 1) {
        if (threadIdx.x < (unsigned)off) sh[threadIdx.x] += sh[threadIdx.x + off];
        __syncthreads();
    }
    if (threadIdx.x == 0) partial[blockIdx.x] = sh[0];
}

__global__ __launch_bounds__(256) void scan2_kernel(int* __restrict__ partial) {
    __shared__ int sh[256];
    int t = threadIdx.x;
    int v = (t < SCAN_NB) ? partial[t] : 0;
    sh[t] = v;
    __syncthreads();
    for (int off = 1; off < 256; off <<= 1) {
        int x = (t >= off) ? sh[t - off] : 0;
        __syncthreads();
        sh[t] += x;
        __syncthreads();
    }
    if (t < SCAN_NB) partial[t] = sh[t] - v;  // exclusive
}

__global__ __launch_bounds__(256) void scan3_kernel(const unsigned long long* __restrict__ pk_in,
                                                    const int* __restrict__ partial,
                                                    int* __restrict__ row_ptr) {
    __shared__ int sh[256];
    int t = threadIdx.x;
    int i = blockIdx.x * 256 + t;
    int v = (i < N_NODES) ? (int)(pk_in[i] >> 48) : 0;
    sh[t] = v;
    __syncthreads();
    for (int off = 1; off < 256; off <<= 1) {
        int x = (t >= off) ? sh[t - off] : 0;
        __syncthreads();
        sh[t] += x;
        __syncthreads();
    }
    if (i < N_NODES) row_ptr[i] = sh[t] - v + partial[blockIdx.x];
    if (i == 0) row_ptr[N_NODES] = N_EDGES;
}

// fused fill + norm: one packed {src, norm} store per CSR slot
__global__ void fill_kernel(const int* __restrict__ ei, const float* __restrict__ ew,
                            const float* __restrict__ deg_out, const float* __restrict__ deg_in,
                            const int* __restrict__ row_ptr, int* __restrict__ cur,
                            int2* __restrict__ csr) {
    int e = blockIdx.x * blockDim.x + threadIdx.x;
    if (e >= N_EDGES) return;
    int s = ei[e];
    int d = ei[N_EDGES + e];
    float nm = ew[e] * rsqrtf(deg_out[s] * deg_in[d] + EPS_F);
    int pos = atomicAdd(&cur[d], 1);
    csr[row_ptr[d] + pos] = make_int2(s, __float_as_int(nm));
}

// ---------------------------------------------------------------------------
// fp16 conversions of inputs (into fragment-swizzled layouts)
// ---------------------------------------------------------------------------

__global__ __launch_bounds__(256) void asplit_kernel(const float* __restrict__ X,
                                                     _Float16* __restrict__ Asw) {
    int tid = blockIdx.x * 256 + threadIdx.x;   // 0 .. N_PAD*32
    int row = tid >> 5, l = tid & 31;
    f16x8 o;
    if (row < N_NODES) {
        const float* p = &X[(size_t)row * 256 + l * 8];
        float4 v0 = *(const float4*)p;
        float4 v1 = *(const float4*)(p + 4);
        o[0] = (_Float16)v0.x; o[1] = (_Float16)v0.y;
        o[2] = (_Float16)v0.z; o[3] = (_Float16)v0.w;
        o[4] = (_Float16)v1.x; o[5] = (_Float16)v1.y;
        o[6] = (_Float16)v1.z; o[7] = (_Float16)v1.w;
    } else {
        o = (f16x8)(_Float16)0.f;
    }
    *(f16x8*)&Asw[swz(row, l)] = o;
}

// W [256k,256n] f32 -> B_sw f16: fragment layout over (col=n, k); 3 weights
__global__ __launch_bounds__(256) void wsplit_kernel(const float* __restrict__ W6,
                                                     const float* __restrict__ W7,
                                                     const float* __restrict__ Wp,
                                                     _Float16* __restrict__ Bsw) {
    int id = blockIdx.x * 256 + threadIdx.x;    // 0..8191 per weight
    int wsel = blockIdx.y;
    const float* W = (wsel == 0) ? W6 : (wsel == 1) ? W7 : Wp;
    int n = id >> 5, l = id & 31;
    f16x8 o;
#pragma unroll
    for (int j = 0; j < 8; ++j)
        o[j] = (_Float16)W[(l * 8 + j) * 256 + n];
    *(f16x8*)&Bsw[(size_t)wsel * 65536 + swz(n, l)] = o;
}

// ---------------------------------------------------------------------------
// fp16 register-resident-B GEMM: C[M,256] = A[M,256] @ W[256,256]
// grid-stride over 16-row panels; 4 waves/block each owning 64 cols;
// B-frags held in VGPRs; no barriers, no staging LDS.
// MODE 0: f16 row-major output. MODE 1: f32 + bias (head).
// ---------------------------------------------------------------------------

template <int MODE>
__global__ __launch_bounds__(256) void gemm_f16(const _Float16* __restrict__ Asw,
                                                const _Float16* __restrict__ Bsw,
                                                const float* __restrict__ bias,
                                                void* __restrict__ Cout, int M) {
    __shared__ _Float16 ebuf[4][16 * 72];   // MODE0 epilogue bounce, row-padded

    const int t = threadIdx.x;
    const int w = t >> 6, lane = t & 63;
    const int lr = lane & 15;

    f16x8 bf[4][8];
#pragma unroll
    for (int cp4 = 0; cp4 < 4; ++cp4)
#pragma unroll
        for (int kb = 0; kb < 8; ++kb)
            bf[cp4][kb] = *(const f16x8*)&Bsw[(size_t)((w * 4 + cp4) * 8 + kb) * 512 + lane * 8];

    float bc[4];
    if (MODE == 1) {
#pragma unroll
        for (int cp4 = 0; cp4 < 4; ++cp4) bc[cp4] = bias[w * 64 + cp4 * 16 + lr];
    }

    for (int p = blockIdx.x; p < N_PANELS; p += gridDim.x) {
        const _Float16* abase = &Asw[(size_t)p * 4096 + lane * 8];
        f16x8 af[8];
#pragma unroll
        for (int kb = 0; kb < 8; ++kb)
            af[kb] = *(const f16x8*)&abase[kb * 512];

        f32x4 acc[4];
#pragma unroll
        for (int cp4 = 0; cp4 < 4; ++cp4) acc[cp4] = (f32x4){0.f, 0.f, 0.f, 0.f};

#pragma unroll
        for (int kb = 0; kb < 8; ++kb)
#pragma unroll
            for (int cp4 = 0; cp4 < 4; ++cp4)
                acc[cp4] = mfma_f16(af[kb], bf[cp4][kb], acc[cp4]);

        // D layout: row = 4*(lane>>4)+reg, col = lane&15  [m89-verified]
        if (MODE == 0) {
            _Float16* eb = ebuf[w];
            const int rq = 4 * (lane >> 4);
#pragma unroll
            for (int cp4 = 0; cp4 < 4; ++cp4)
#pragma unroll
                for (int rr = 0; rr < 4; ++rr)
                    eb[(rq + rr) * 72 + cp4 * 16 + lr] = (_Float16)acc[cp4][rr];
            _Float16* xp = (_Float16*)Cout;
#pragma unroll
            for (int it = 0; it < 2; ++it) {
                int rl = it * 8 + (lane >> 3);
                f16x8 v = *(const f16x8*)&eb[rl * 72 + (lane & 7) * 8];
                *(f16x8*)&xp[(size_t)(p * 16 + rl) * 256 + w * 64 + (lane & 7) * 8] = v;
            }
        } else {
            float* op = (float*)Cout;
            const int rbase = p * 16 + 4 * (lane >> 4);
#pragma unroll
            for (int cp4 = 0; cp4 < 4; ++cp4) {
                const int col = w * 64 + cp4 * 16 + lr;
#pragma unroll
                for (int rr = 0; rr < 4; ++rr) {
                    int row = rbase + rr;
                    if (row < M) op[(size_t)row * 256 + col] = acc[cp4][rr] + bc[cp4];
                }
            }
        }
    }
}

// ---------------------------------------------------------------------------
// Aggregation: 8 nodes/block, 32 lanes/node, 8 features/lane (f16x8),
// 4 independent edge gathers in flight; packed {src,norm} CSR headers.
// ---------------------------------------------------------------------------

__global__ __launch_bounds__(256) void agg_kernel(const _Float16* __restrict__ xt,
                                                  const int* __restrict__ row_ptr,
                                                  const int2* __restrict__ csr,
                                                  const float* __restrict__ bias,
                                                  _Float16* __restrict__ Asw) {
    const int g = threadIdx.x >> 5;
    const int l = threadIdx.x & 31;
    const int v = blockIdx.x * 8 + g;
    const int d0 = l * 8;

    const int s0 = row_ptr[v];
    const int s1 = row_ptr[v + 1];

    float acc[8] = {0.f, 0.f, 0.f, 0.f, 0.f, 0.f, 0.f, 0.f};

    int i = s0;
    for (; i + 4 <= s1; i += 4) {
        int2 hd[4];
#pragma unroll
        for (int u = 0; u < 4; ++u) hd[u] = csr[i + u];
        f16x8 val[4];
#pragma unroll
        for (int u = 0; u < 4; ++u)
            val[u] = *(const f16x8*)&xt[(size_t)hd[u].x * 256 + d0];
#pragma unroll
        for (int u = 0; u < 4; ++u) {
            float wv = __int_as_float(hd[u].y);
#pragma unroll
            for (int j = 0; j < 8; ++j)
                acc[j] += (float)val[u][j] * wv;
        }
    }
    {
        int rem = s1 - i;
        int2 hd[3];
#pragma unroll
        for (int u = 0; u < 3; ++u)
            hd[u] = (u < rem) ? csr[i + u] : make_int2(0, 0);
        f16x8 val[3];
#pragma unroll
        for (int u = 0; u < 3; ++u)
            val[u] = *(const f16x8*)&xt[(size_t)hd[u].x * 256 + d0];
#pragma unroll
        for (int u = 0; u < 3; ++u) {
            float wv = __int_as_float(hd[u].y);
#pragma unroll
            for (int j = 0; j < 8; ++j)
                acc[j] += (float)val[u][j] * wv;
        }
    }

    f16x8 o;
#pragma unroll
    for (int j = 0; j < 8; ++j) {
        float r = acc[j] + bias[d0 + j];
        r = r > 0.f ? r : 0.f;
        o[j] = (_Float16)r;
    }
    *(f16x8*)&Asw[swz(v, l)] = o;
}

// ---------------------------------------------------------------------------

extern "C" void kernel_launch(void* const* d_in, const int* in_sizes, int n_in,
                              void* d_out, int out_size, void* d_ws, size_t ws_size,
                              hipStream_t stream) {
    (void)in_sizes; (void)n_in; (void)out_size; (void)ws_size;
    const float* h5 = (const float*)d_in[0];
    const int*   ei = (const int*)d_in[1];
    const float* ew = (const float*)d_in[2];
    const float* W6 = (const float*)d_in[3];
    const float* b6 = (const float*)d_in[4];
    const float* W7 = (const float*)d_in[5];
    const float* b7 = (const float*)d_in[6];
    const float* Wp = (const float*)d_in[7];
    const float* bp = (const float*)d_in[8];
    float* out = (float*)d_out;

    char* ws = (char*)d_ws;
    size_t off = 0;
    auto alloc = [&](size_t bytes) -> void* {
        void* p = ws + off;
        off = (off + bytes + 255) & ~(size_t)255;
        return p;
    };

    // single zeroed region: pk_out (400K) | pk_in (400K) | cur (200K)
    char* zblk = (char*)alloc(ZBYTES);
    unsigned long long* pk_out = (unsigned long long*)zblk;
    unsigned long long* pk_in  = (unsigned long long*)(zblk + N_NODES * 8);
    int* cur = (int*)(zblk + N_NODES * 16);

    float* deg_out = (float*)alloc(N_NODES * 4);
    float* deg_in  = (float*)alloc(N_NODES * 4);
    int*   row_ptr = (int*)alloc((N_NODES + 1) * 4);
    int*   partial = (int*)alloc(SCAN_NB * 4);
    int2*  csr     = (int2*)alloc(N_EDGES * 8);
    _Float16* Bsw  = (_Float16*)alloc(3 * 65536 * 2);
    _Float16* Asw  = (_Float16*)alloc((size_t)N_PAD * 256 * 2);
    _Float16* xt   = (_Float16*)alloc((size_t)N_PAD * 256 * 2);

    const int EB = (N_EDGES + 255) / 256;
    const int GB = 512;   // gemm grid (grid-stride over 3128 panels)
    const int Z16 = ZBYTES / 16;   // 62500 int4s

    zero_kernel<<<(Z16 + 255) / 256, 256, 0, stream>>>((int4*)zblk, Z16);

    deg_kernel<<<EB, 256, 0, stream>>>(ei, ew, pk_out, pk_in);
    scan1_kernel<<<SCAN_NB, 256, 0, stream>>>(pk_in, pk_out, deg_in, deg_out, partial);
    scan2_kernel<<<1, 256, 0, stream>>>(partial);
    scan3_kernel<<<SCAN_NB, 256, 0, stream>>>(pk_in, partial, row_ptr);
    fill_kernel<<<EB, 256, 0, stream>>>(ei, ew, deg_out, deg_in, row_ptr, cur, csr);

    // input conversions
    asplit_kernel<<<N_PAD * 32 / 256, 256, 0, stream>>>(h5, Asw);
    wsplit_kernel<<<dim3(32, 3), 256, 0, stream>>>(W6, W7, Wp, Bsw);

    // layer 1
    gemm_f16<0><<<GB, 256, 0, stream>>>(Asw, Bsw, nullptr, xt, N_PAD);
    agg_kernel<<<N_NODES / 8, 256, 0, stream>>>(xt, row_ptr, csr, b6, Asw);

    // layer 2
    gemm_f16<0><<<GB, 256, 0, stream>>>(Asw, Bsw + 65536, nullptr, xt, N_PAD);
    agg_kernel<<<N_NODES / 8, 256, 0, stream>>>(xt, row_ptr, csr, b7, Asw);

    // head
    gemm_f16<1><<<GB, 256, 0, stream>>>(Asw, Bsw + 2 * 65536, bp, out, N_NODES);
}

// Round 9
// 170.852 us; speedup vs baseline: 3.4954x; 1.0691x over previous
//
#include <hip/hip_runtime.h>

#define N_NODES 50000
#define N_PAD   50048
#define N_PANELS 3125            // 50000 / 16 exactly
#define N_EDGES 300000
#define EPS_F 1e-12f
#define EB ((N_EDGES + 255) / 256)        // 1172 edge-blocks
#define GB 512                            // gemm grid (grid-stride over panels)
#define SCAN_NB ((N_NODES + 255) / 256)   // 196
#define MASK48 ((1ull << 48) - 1)
#define ZBYTES (N_NODES * 20)             // pk_out(8) + pk_in(8) + cur(4)

typedef _Float16 f16x8 __attribute__((ext_vector_type(8)));
typedef float f32x4 __attribute__((ext_vector_type(4)));

static __device__ inline f32x4 mfma_f16(f16x8 a, f16x8 b, f32x4 c) {
    return __builtin_amdgcn_mfma_f32_16x16x32_f16(a, b, c, 0, 0, 0);
}

// fragment-ready swizzled layout for a [R][256] f16 matrix:
// element (row, k) at ((row>>4)*8 + (k>>5))*512 + ((k>>3)&3)*128 + (row&15)*8 + (k&7)
static __device__ inline size_t swz(int row, int l) {
    return ((size_t)(row >> 4) * 8 + (l >> 2)) * 512 + (size_t)((l & 3) * 128 + (row & 15) * 8);
}

// ---------------------------------------------------------------------------
// Workspace zero-init
// ---------------------------------------------------------------------------

__global__ __launch_bounds__(256) void zero_kernel(int4* __restrict__ p, int n16) {
    int i = blockIdx.x * 256 + threadIdx.x;
    if (i < n16) p[i] = make_int4(0, 0, 0, 0);
}

// ---------------------------------------------------------------------------
// P1: deg (packed fixed-point atomics) ∥ wsplit (W -> swizzled f16 fragments)
// ---------------------------------------------------------------------------

__global__ __launch_bounds__(256) void p1_kernel(const int* __restrict__ ei,
                                                 const float* __restrict__ ew,
                                                 unsigned long long* __restrict__ pk_out,
                                                 unsigned long long* __restrict__ pk_in,
                                                 const float* __restrict__ W6,
                                                 const float* __restrict__ W7,
                                                 const float* __restrict__ Wp,
                                                 _Float16* __restrict__ Bsw) {
    int b = blockIdx.x;
    if (b < EB) {
        int e = b * 256 + threadIdx.x;
        if (e >= N_EDGES) return;
        int s = ei[e];
        int d = ei[N_EDGES + e];
        unsigned long long wfx = (unsigned long long)(ew[e] * 4294967296.0f);
        atomicAdd(&pk_out[s], wfx);
        atomicAdd(&pk_in[d], (1ull << 48) | wfx);
    } else {
        int bb = b - EB;                  // 0..95
        int wsel = bb >> 5;               // 0..2
        const float* W = (wsel == 0) ? W6 : (wsel == 1) ? W7 : Wp;
        int id = (bb & 31) * 256 + threadIdx.x;   // 0..8191
        int n = id >> 5, l = id & 31;
        f16x8 o;
#pragma unroll
        for (int j = 0; j < 8; ++j)
            o[j] = (_Float16)W[(l * 8 + j) * 256 + n];
        *(f16x8*)&Bsw[(size_t)wsel * 65536 + swz(n, l)] = o;
    }
}

// --- scan: per-block reduce, then fused (partial-scan + local scan) ---------

__global__ __launch_bounds__(256) void scan1_kernel(const unsigned long long* __restrict__ pk_in,
                                                    const unsigned long long* __restrict__ pk_out,
                                                    float* __restrict__ deg_in,
                                                    float* __restrict__ deg_out,
                                                    int* __restrict__ partial) {
    __shared__ int sh[256];
    int i = blockIdx.x * 256 + threadIdx.x;
    int c = 0;
    if (i < N_NODES) {
        unsigned long long p = pk_in[i];
        c = (int)(p >> 48);
        deg_in[i] = (float)(p & MASK48) * 0x1p-32f;
        deg_out[i] = (float)pk_out[i] * 0x1p-32f;
    }
    sh[threadIdx.x] = c;
    __syncthreads();
    for (int off = 128; off > 0; off >>= 1) {
        if (threadIdx.x < (unsigned)off) sh[threadIdx.x] += sh[threadIdx.x + off];
        __syncthreads();
    }
    if (threadIdx.x == 0) partial[blockIdx.x] = sh[0];
}

// fused scan2+scan3: every block redundantly scans the 196 partials (trivial)
__global__ __launch_bounds__(256) void scan23_kernel(const unsigned long long* __restrict__ pk_in,
                                                     const int* __restrict__ partial,
                                                     int* __restrict__ row_ptr) {
    __shared__ int ps[256];
    __shared__ int sh[256];
    int t = threadIdx.x;
    int pv = (t < SCAN_NB) ? partial[t] : 0;
    ps[t] = pv;
    __syncthreads();
    for (int off = 1; off < 256; off <<= 1) {
        int x = (t >= off) ? ps[t - off] : 0;
        __syncthreads();
        ps[t] += x;
        __syncthreads();
    }
    int incl = ps[t];
    __syncthreads();
    ps[t] = incl - pv;    // exclusive prefix of partials
    __syncthreads();
    const int boff = ps[blockIdx.x];

    int i = blockIdx.x * 256 + t;
    int v = (i < N_NODES) ? (int)(pk_in[i] >> 48) : 0;
    sh[t] = v;
    __syncthreads();
    for (int off = 1; off < 256; off <<= 1) {
        int x = (t >= off) ? sh[t - off] : 0;
        __syncthreads();
        sh[t] += x;
        __syncthreads();
    }
    if (i < N_NODES) row_ptr[i] = sh[t] - v + boff;
    if (i == 0) row_ptr[N_NODES] = N_EDGES;
}

// ---------------------------------------------------------------------------
// P2: fill (fused norm, packed {src,norm} CSR) ∥ gemm layer-1
// gemm reads h5 f32 row-major directly (conversion folded in), B-frags in
// VGPRs, writes f16 row-major xt via LDS bounce. 50000 = 3125*16: no pad.
// ---------------------------------------------------------------------------

__global__ __launch_bounds__(256) void p2_kernel(const int* __restrict__ ei,
                                                 const float* __restrict__ ew,
                                                 const float* __restrict__ deg_out,
                                                 const float* __restrict__ deg_in,
                                                 const int* __restrict__ row_ptr,
                                                 int* __restrict__ cur,
                                                 int2* __restrict__ csr,
                                                 const float* __restrict__ h5,
                                                 const _Float16* __restrict__ Bsw,
                                                 _Float16* __restrict__ xt) {
    __shared__ _Float16 ebuf[4][16 * 72];

    if (blockIdx.x < EB) {
        int e = blockIdx.x * 256 + threadIdx.x;
        if (e >= N_EDGES) return;
        int s = ei[e];
        int d = ei[N_EDGES + e];
        float nm = ew[e] * rsqrtf(deg_out[s] * deg_in[d] + EPS_F);
        int pos = atomicAdd(&cur[d], 1);
        csr[row_ptr[d] + pos] = make_int2(s, __float_as_int(nm));
        return;
    }

    const int t = threadIdx.x;
    const int w = t >> 6, lane = t & 63;

    f16x8 bf[4][8];
#pragma unroll
    for (int cp4 = 0; cp4 < 4; ++cp4)
#pragma unroll
        for (int kb = 0; kb < 8; ++kb)
            bf[cp4][kb] = *(const f16x8*)&Bsw[(size_t)((w * 4 + cp4) * 8 + kb) * 512 + lane * 8];

    for (int p = blockIdx.x - EB; p < N_PANELS; p += GB) {
        const float* ab = &h5[(size_t)(p * 16 + (lane & 15)) * 256 + (lane >> 4) * 8];
        f16x8 af[8];
#pragma unroll
        for (int kb = 0; kb < 8; ++kb) {
            float4 v0 = *(const float4*)(ab + kb * 32);
            float4 v1 = *(const float4*)(ab + kb * 32 + 4);
            f16x8 a;
            a[0] = (_Float16)v0.x; a[1] = (_Float16)v0.y;
            a[2] = (_Float16)v0.z; a[3] = (_Float16)v0.w;
            a[4] = (_Float16)v1.x; a[5] = (_Float16)v1.y;
            a[6] = (_Float16)v1.z; a[7] = (_Float16)v1.w;
            af[kb] = a;
        }

        f32x4 acc[4];
#pragma unroll
        for (int cp4 = 0; cp4 < 4; ++cp4) acc[cp4] = (f32x4){0.f, 0.f, 0.f, 0.f};
#pragma unroll
        for (int kb = 0; kb < 8; ++kb)
#pragma unroll
            for (int cp4 = 0; cp4 < 4; ++cp4)
                acc[cp4] = mfma_f16(af[kb], bf[cp4][kb], acc[cp4]);

        // D: row = 4*(lane>>4)+reg, col = lane&15  [m89-verified]
        _Float16* eb = ebuf[w];
        const int rq = 4 * (lane >> 4);
        const int lr = lane & 15;
#pragma unroll
        for (int cp4 = 0; cp4 < 4; ++cp4)
#pragma unroll
            for (int rr = 0; rr < 4; ++rr)
                eb[(rq + rr) * 72 + cp4 * 16 + lr] = (_Float16)acc[cp4][rr];
#pragma unroll
        for (int it = 0; it < 2; ++it) {
            int rl = it * 8 + (lane >> 3);
            f16x8 v = *(const f16x8*)&eb[rl * 72 + (lane & 7) * 8];
            *(f16x8*)&xt[(size_t)(p * 16 + rl) * 256 + w * 64 + (lane & 7) * 8] = v;
        }
    }
}

// ---------------------------------------------------------------------------
// gemm (swizzled f16 A): MODE 0 -> f16 row-major xt; MODE 1 -> f32 + bias out
// ---------------------------------------------------------------------------

template <int MODE>
__global__ __launch_bounds__(256) void gemm_f16(const _Float16* __restrict__ Asw,
                                                const _Float16* __restrict__ Bsw,
                                                const float* __restrict__ bias,
                                                void* __restrict__ Cout) {
    __shared__ _Float16 ebuf[4][16 * 72];

    const int t = threadIdx.x;
    const int w = t >> 6, lane = t & 63;
    const int lr = lane & 15;

    f16x8 bf[4][8];
#pragma unroll
    for (int cp4 = 0; cp4 < 4; ++cp4)
#pragma unroll
        for (int kb = 0; kb < 8; ++kb)
            bf[cp4][kb] = *(const f16x8*)&Bsw[(size_t)((w * 4 + cp4) * 8 + kb) * 512 + lane * 8];

    float bc[4];
    if (MODE == 1) {
#pragma unroll
        for (int cp4 = 0; cp4 < 4; ++cp4) bc[cp4] = bias[w * 64 + cp4 * 16 + lr];
    }

    for (int p = blockIdx.x; p < N_PANELS; p += GB) {
        const _Float16* abase = &Asw[(size_t)p * 4096 + lane * 8];
        f16x8 af[8];
#pragma unroll
        for (int kb = 0; kb < 8; ++kb)
            af[kb] = *(const f16x8*)&abase[kb * 512];

        f32x4 acc[4];
#pragma unroll
        for (int cp4 = 0; cp4 < 4; ++cp4) acc[cp4] = (f32x4){0.f, 0.f, 0.f, 0.f};
#pragma unroll
        for (int kb = 0; kb < 8; ++kb)
#pragma unroll
            for (int cp4 = 0; cp4 < 4; ++cp4)
                acc[cp4] = mfma_f16(af[kb], bf[cp4][kb], acc[cp4]);

        if (MODE == 0) {
            _Float16* eb = ebuf[w];
            const int rq = 4 * (lane >> 4);
#pragma unroll
            for (int cp4 = 0; cp4 < 4; ++cp4)
#pragma unroll
                for (int rr = 0; rr < 4; ++rr)
                    eb[(rq + rr) * 72 + cp4 * 16 + lr] = (_Float16)acc[cp4][rr];
            _Float16* xp = (_Float16*)Cout;
#pragma unroll
            for (int it = 0; it < 2; ++it) {
                int rl = it * 8 + (lane >> 3);
                f16x8 v = *(const f16x8*)&eb[rl * 72 + (lane & 7) * 8];
                *(f16x8*)&xp[(size_t)(p * 16 + rl) * 256 + w * 64 + (lane & 7) * 8] = v;
            }
        } else {
            float* op = (float*)Cout;
            const int rbase = p * 16 + 4 * (lane >> 4);
#pragma unroll
            for (int cp4 = 0; cp4 < 4; ++cp4) {
                const int col = w * 64 + cp4 * 16 + lr;
#pragma unroll
                for (int rr = 0; rr < 4; ++rr)
                    op[(size_t)(rbase + rr) * 256 + col] = acc[cp4][rr] + bc[cp4];
            }
        }
    }
}

// ---------------------------------------------------------------------------
// Aggregation: 8 nodes/block, 32 lanes/node, 8 features/lane, 4 gathers in
// flight; packed {src,norm} headers; writes fragment-swizzled f16 output.
// ---------------------------------------------------------------------------

__global__ __launch_bounds__(256) void agg_kernel(const _Float16* __restrict__ xt,
                                                  const int* __restrict__ row_ptr,
                                                  const int2* __restrict__ csr,
                                                  const float* __restrict__ bias,
                                                  _Float16* __restrict__ Asw) {
    const int g = threadIdx.x >> 5;
    const int l = threadIdx.x & 31;
    const int v = blockIdx.x * 8 + g;
    const int d0 = l * 8;

    const int s0 = row_ptr[v];
    const int s1 = row_ptr[v + 1];

    float acc[8] = {0.f, 0.f, 0.f, 0.f, 0.f, 0.f, 0.f, 0.f};

    int i = s0;
    for (; i + 4 <= s1; i += 4) {
        int2 hd[4];
#pragma unroll
        for (int u = 0; u < 4; ++u) hd[u] = csr[i + u];
        f16x8 val[4];
#pragma unroll
        for (int u = 0; u < 4; ++u)
            val[u] = *(const f16x8*)&xt[(size_t)hd[u].x * 256 + d0];
#pragma unroll
        for (int u = 0; u < 4; ++u) {
            float wv = __int_as_float(hd[u].y);
#pragma unroll
            for (int j = 0; j < 8; ++j)
                acc[j] += (float)val[u][j] * wv;
        }
    }
    {
        int rem = s1 - i;
        int2 hd[3];
#pragma unroll
        for (int u = 0; u < 3; ++u)
            hd[u] = (u < rem) ? csr[i + u] : make_int2(0, 0);
        f16x8 val[3];
#pragma unroll
        for (int u = 0; u < 3; ++u)
            val[u] = *(const f16x8*)&xt[(size_t)hd[u].x * 256 + d0];
#pragma unroll
        for (int u = 0; u < 3; ++u) {
            float wv = __int_as_float(hd[u].y);
#pragma unroll
            for (int j = 0; j < 8; ++j)
                acc[j] += (float)val[u][j] * wv;
        }
    }

    f16x8 o;
#pragma unroll
    for (int j = 0; j < 8; ++j) {
        float r = acc[j] + bias[d0 + j];
        r = r > 0.f ? r : 0.f;
        o[j] = (_Float16)r;
    }
    *(f16x8*)&Asw[swz(v, l)] = o;
}

// ---------------------------------------------------------------------------

extern "C" void kernel_launch(void* const* d_in, const int* in_sizes, int n_in,
                              void* d_out, int out_size, void* d_ws, size_t ws_size,
                              hipStream_t stream) {
    (void)in_sizes; (void)n_in; (void)out_size; (void)ws_size;
    const float* h5 = (const float*)d_in[0];
    const int*   ei = (const int*)d_in[1];
    const float* ew = (const float*)d_in[2];
    const float* W6 = (const float*)d_in[3];
    const float* b6 = (const float*)d_in[4];
    const float* W7 = (const float*)d_in[5];
    const float* b7 = (const float*)d_in[6];
    const float* Wp = (const float*)d_in[7];
    const float* bp = (const float*)d_in[8];
    float* out = (float*)d_out;

    char* ws = (char*)d_ws;
    size_t off = 0;
    auto alloc = [&](size_t bytes) -> void* {
        void* p = ws + off;
        off = (off + bytes + 255) & ~(size_t)255;
        return p;
    };

    // single zeroed region: pk_out | pk_in | cur
    char* zblk = (char*)alloc(ZBYTES);
    unsigned long long* pk_out = (unsigned long long*)zblk;
    unsigned long long* pk_in  = (unsigned long long*)(zblk + N_NODES * 8);
    int* cur = (int*)(zblk + N_NODES * 16);

    float* deg_out = (float*)alloc(N_NODES * 4);
    float* deg_in  = (float*)alloc(N_NODES * 4);
    int*   row_ptr = (int*)alloc((N_NODES + 1) * 4);
    int*   partial = (int*)alloc(SCAN_NB * 4);
    int2*  csr     = (int2*)alloc(N_EDGES * 8);
    _Float16* Bsw  = (_Float16*)alloc(3 * 65536 * 2);
    _Float16* Asw  = (_Float16*)alloc((size_t)N_PAD * 256 * 2);
    _Float16* xt   = (_Float16*)alloc((size_t)N_PAD * 256 * 2);

    const int Z16 = ZBYTES / 16;

    zero_kernel<<<(Z16 + 255) / 256, 256, 0, stream>>>((int4*)zblk, Z16);

    // deg ∥ wsplit
    p1_kernel<<<EB + 96, 256, 0, stream>>>(ei, ew, pk_out, pk_in, W6, W7, Wp, Bsw);
    scan1_kernel<<<SCAN_NB, 256, 0, stream>>>(pk_in, pk_out, deg_in, deg_out, partial);
    scan23_kernel<<<SCAN_NB, 256, 0, stream>>>(pk_in, partial, row_ptr);

    // fill ∥ gemm layer-1 (reads h5 f32 directly)
    p2_kernel<<<EB + GB, 256, 0, stream>>>(ei, ew, deg_out, deg_in, row_ptr, cur, csr,
                                           h5, Bsw, xt);

    agg_kernel<<<N_NODES / 8, 256, 0, stream>>>(xt, row_ptr, csr, b6, Asw);
    gemm_f16<0><<<GB, 256, 0, stream>>>(Asw, Bsw + 65536, nullptr, xt);
    agg_kernel<<<N_NODES / 8, 256, 0, stream>>>(xt, row_ptr, csr, b7, Asw);
    gemm_f16<1><<<GB, 256, 0, stream>>>(Asw, Bsw + 2 * 65536, bp, out);
}